// Round 1
// baseline (975.804 us; speedup 1.0000x reference)
//
#include <hip/hip_runtime.h>
#include <hip/hip_bf16.h>
#include <math.h>

#define SEQ   2048
#define NB    4
#define CDIM  512
#define NHEAD 8
#define HD    64
// scale * log2(e): softmax computed in exp2/log2 domain throughout
#define SL    (0.125f * 1.4426950408889634f)

// ---------------------------------------------------------------------------
// Generic fp32 GEMM: C[b] = A @ B[b] (+ bias), A:[M][K], B:[K][N], C:[M][N]
// 128x128 tile, BK=16, 256 threads, 8x8 per thread.
// ---------------------------------------------------------------------------
template<bool HAS_BIAS>
__global__ __launch_bounds__(256)
void gemm128(const float* __restrict__ A, const float* __restrict__ B,
             float* __restrict__ C, const float* __restrict__ bias,
             int M, int N, int K)
{
    const int bn  = blockIdx.x * 128;
    const int bm  = blockIdx.y * 128;
    const int bat = blockIdx.z;
    const float* Bp = B + (size_t)bat * K * N;
    float*       Cp = C + (size_t)bat * M * N;

    __shared__ __align__(16) float As[16][128];
    __shared__ __align__(16) float Bs[16][128];

    const int tid = threadIdx.x;
    const int tm  = (tid >> 4) << 3;   // 0..120
    const int tn  = (tid & 15) << 3;

    float acc[8][8] = {};

    for (int k0 = 0; k0 < K; k0 += 16) {
        // A tile 128x16 -> As[k][m] (transposed)
        #pragma unroll
        for (int s = 0; s < 2; ++s) {
            int f4 = tid * 2 + s;             // 0..511
            int m  = f4 >> 2;                 // 0..127
            int kc = (f4 & 3) << 2;           // 0,4,8,12
            float4 a = *(const float4*)(A + (size_t)(bm + m) * K + k0 + kc);
            As[kc + 0][m] = a.x; As[kc + 1][m] = a.y;
            As[kc + 2][m] = a.z; As[kc + 3][m] = a.w;
        }
        // B tile 16x128 -> Bs[k][n]
        #pragma unroll
        for (int s = 0; s < 2; ++s) {
            int f4 = tid * 2 + s;
            int kk = f4 >> 5;                 // 0..15
            int n  = (f4 & 31) << 2;          // 0..124
            *(float4*)&Bs[kk][n] =
                *(const float4*)(Bp + (size_t)(k0 + kk) * N + bn + n);
        }
        __syncthreads();
        #pragma unroll
        for (int kk = 0; kk < 16; ++kk) {
            float4 a0 = *(const float4*)&As[kk][tm];
            float4 a1 = *(const float4*)&As[kk][tm + 4];
            float4 b0 = *(const float4*)&Bs[kk][tn];
            float4 b1 = *(const float4*)&Bs[kk][tn + 4];
            float av[8] = {a0.x, a0.y, a0.z, a0.w, a1.x, a1.y, a1.z, a1.w};
            float bv[8] = {b0.x, b0.y, b0.z, b0.w, b1.x, b1.y, b1.z, b1.w};
            #pragma unroll
            for (int i = 0; i < 8; ++i)
                #pragma unroll
                for (int j = 0; j < 8; ++j)
                    acc[i][j] = fmaf(av[i], bv[j], acc[i][j]);
        }
        __syncthreads();
    }

    #pragma unroll
    for (int i = 0; i < 8; ++i) {
        float bi = HAS_BIAS ? bias[bm + tm + i] : 0.0f;
        #pragma unroll
        for (int j = 0; j < 8; ++j) acc[i][j] += bi;
        float* row = Cp + (size_t)(bm + tm + i) * N + bn + tn;
        *(float4*)(row + 0) = make_float4(acc[i][0], acc[i][1], acc[i][2], acc[i][3]);
        *(float4*)(row + 4) = make_float4(acc[i][4], acc[i][5], acc[i][6], acc[i][7]);
    }
}

// ---------------------------------------------------------------------------
// Pass 1: per (b,h, i-tile of 64 keys) compute c_i = m_i + log2 sum_j 2^(S*SL - m_i)
// S[i,j] = (k_i . q_j); softmax axis is j (all 2048 queries).
// ---------------------------------------------------------------------------
__global__ __launch_bounds__(256)
void attn_pass1(const float* __restrict__ qkv, float* __restrict__ cvals)
{
    const int it = blockIdx.x;            // i-tile index (64 keys)
    const int bh = blockIdx.y;            // b*8 + h
    const int b  = bh >> 3, h = bh & 7;
    const float* qb = qkv + ((size_t)b * (3 * CDIM) + h * 192) * SEQ;
    const float* kb = qb + (size_t)64 * SEQ;
    const int i0 = it * 64;

    __shared__ __align__(16) float Ks[64][64];    // K[d][i]
    __shared__ __align__(16) float Qs[64][128];   // Q[d][j]
    __shared__ float redm[64][16];
    __shared__ float redl[64][16];

    const int tid = threadIdx.x;

    // load K tile once: [d][i], rows contiguous
    #pragma unroll
    for (int s = 0; s < 4; ++s) {
        int f4 = s * 256 + tid;           // 1024 float4s
        int d = f4 >> 4, c = (f4 & 15) << 2;
        *(float4*)&Ks[d][c] = *(const float4*)(kb + (size_t)d * SEQ + i0 + c);
    }

    const int ti = (tid >> 4) << 2;       // 4 i-rows
    const int tj = (tid & 15) << 3;       // 8 j-cols
    float m[4], l[4];
    #pragma unroll
    for (int r = 0; r < 4; ++r) { m[r] = -1e30f; l[r] = 0.f; }

    for (int jt = 0; jt < 16; ++jt) {
        const int j0 = jt * 128;
        __syncthreads();                  // protect Qs readers / make Ks visible
        #pragma unroll
        for (int s = 0; s < 8; ++s) {
            int f4 = s * 256 + tid;       // 2048 float4s
            int d = f4 >> 5, c = (f4 & 31) << 2;
            *(float4*)&Qs[d][c] = *(const float4*)(qb + (size_t)d * SEQ + j0 + c);
        }
        __syncthreads();

        float sacc[4][8] = {};
        #pragma unroll 8
        for (int d = 0; d < 64; ++d) {
            float4 kv = *(const float4*)&Ks[d][ti];
            float4 q0 = *(const float4*)&Qs[d][tj];
            float4 q1 = *(const float4*)&Qs[d][tj + 4];
            float kr[4] = {kv.x, kv.y, kv.z, kv.w};
            float qr[8] = {q0.x, q0.y, q0.z, q0.w, q1.x, q1.y, q1.z, q1.w};
            #pragma unroll
            for (int r = 0; r < 4; ++r)
                #pragma unroll
                for (int c = 0; c < 8; ++c)
                    sacc[r][c] = fmaf(kr[r], qr[c], sacc[r][c]);
        }
        // online (m,l) update in log2 domain
        #pragma unroll
        for (int r = 0; r < 4; ++r) {
            float mt = m[r];
            #pragma unroll
            for (int c = 0; c < 8; ++c) mt = fmaxf(mt, sacc[r][c] * SL);
            l[r] *= exp2f(m[r] - mt);
            float ls = 0.f;
            #pragma unroll
            for (int c = 0; c < 8; ++c) ls += exp2f(sacc[r][c] * SL - mt);
            l[r] += ls;
            m[r] = mt;
        }
    }

    #pragma unroll
    for (int r = 0; r < 4; ++r) {
        redm[ti + r][tid & 15] = m[r];
        redl[ti + r][tid & 15] = l[r];
    }
    __syncthreads();
    if (tid < 64) {
        float M = -1e30f;
        #pragma unroll
        for (int t = 0; t < 16; ++t) M = fmaxf(M, redm[tid][t]);
        float L = 0.f;
        #pragma unroll
        for (int t = 0; t < 16; ++t) L += redl[tid][t] * exp2f(redm[tid][t] - M);
        cvals[(size_t)bh * SEQ + i0 + tid] = M + log2f(L);
    }
}

// ---------------------------------------------------------------------------
// Pass 2: per (b,h, j-tile of 64 queries): out[d,j] = sum_i v[d,i]*2^(S*SL - c_i)
// ---------------------------------------------------------------------------
__global__ __launch_bounds__(256)
void attn_pass2(const float* __restrict__ qkv, const float* __restrict__ cvals,
                float* __restrict__ aout)
{
    const int jt = blockIdx.x;
    const int bh = blockIdx.y;
    const int b  = bh >> 3, h = bh & 7;
    const float* qb = qkv + ((size_t)b * (3 * CDIM) + h * 192) * SEQ;
    const float* kb = qb + (size_t)64 * SEQ;
    const float* vb = qb + (size_t)128 * SEQ;
    float* ob = aout + ((size_t)b * CDIM + h * HD) * SEQ;
    const int j0 = jt * 64;

    __shared__ __align__(16) float Qs[64][64];   // Q[d][j]
    __shared__ __align__(16) float Ks[64][64];   // K[d][i]
    __shared__ __align__(16) float Vt[64][68];   // V^T[i][d], padded
    __shared__ __align__(16) float Ps[64][64];   // P[i][j]
    __shared__ float cs[64];

    const int tid = threadIdx.x;

    // load Q tile once
    #pragma unroll
    for (int s = 0; s < 4; ++s) {
        int f4 = s * 256 + tid;
        int d = f4 >> 4, c = (f4 & 15) << 2;
        *(float4*)&Qs[d][c] = *(const float4*)(qb + (size_t)d * SEQ + j0 + c);
    }

    const int ti = (tid >> 4) << 2;   // S rows (i); also out d-rows
    const int tj = (tid & 15) << 2;   // S cols (j); also out j-cols
    float acc[4][4] = {};

    for (int it = 0; it < 32; ++it) {
        const int i0 = it * 64;
        __syncthreads();              // protect Ks/Vt/Ps/cs from prev iter readers
        #pragma unroll
        for (int s = 0; s < 4; ++s) {
            int f4 = s * 256 + tid;
            int d = f4 >> 4, c = (f4 & 15) << 2;
            *(float4*)&Ks[d][c] = *(const float4*)(kb + (size_t)d * SEQ + i0 + c);
            float4 v = *(const float4*)(vb + (size_t)d * SEQ + i0 + c);
            Vt[c + 0][d] = v.x; Vt[c + 1][d] = v.y;
            Vt[c + 2][d] = v.z; Vt[c + 3][d] = v.w;
        }
        if (tid < 64) cs[tid] = cvals[(size_t)bh * SEQ + i0 + tid];
        __syncthreads();

        // S sub-tile 4x4
        float sacc[4][4] = {};
        #pragma unroll 8
        for (int d = 0; d < 64; ++d) {
            float4 kv = *(const float4*)&Ks[d][ti];
            float4 qv = *(const float4*)&Qs[d][tj];
            float kr[4] = {kv.x, kv.y, kv.z, kv.w};
            float qr[4] = {qv.x, qv.y, qv.z, qv.w};
            #pragma unroll
            for (int r = 0; r < 4; ++r)
                #pragma unroll
                for (int c = 0; c < 4; ++c)
                    sacc[r][c] = fmaf(kr[r], qr[c], sacc[r][c]);
        }
        // P = 2^(S*SL - c_i)
        #pragma unroll
        for (int r = 0; r < 4; ++r) {
            float cc = cs[ti + r];
            float4 p;
            p.x = exp2f(sacc[r][0] * SL - cc);
            p.y = exp2f(sacc[r][1] * SL - cc);
            p.z = exp2f(sacc[r][2] * SL - cc);
            p.w = exp2f(sacc[r][3] * SL - cc);
            *(float4*)&Ps[ti + r][tj] = p;
        }
        __syncthreads();

        // out[d,j] += V[d,i] * P[i,j]
        #pragma unroll 8
        for (int i = 0; i < 64; ++i) {
            float4 vv = *(const float4*)&Vt[i][ti];
            float4 pp = *(const float4*)&Ps[i][tj];
            float vr[4] = {vv.x, vv.y, vv.z, vv.w};
            float pr[4] = {pp.x, pp.y, pp.z, pp.w};
            #pragma unroll
            for (int r = 0; r < 4; ++r)
                #pragma unroll
                for (int c = 0; c < 4; ++c)
                    acc[r][c] = fmaf(vr[r], pr[c], acc[r][c]);
        }
    }

    #pragma unroll
    for (int r = 0; r < 4; ++r) {
        *(float4*)(ob + (size_t)(ti + r) * SEQ + j0 + tj) =
            make_float4(acc[r][0], acc[r][1], acc[r][2], acc[r][3]);
    }
}

// ---------------------------------------------------------------------------
extern "C" void kernel_launch(void* const* d_in, const int* in_sizes, int n_in,
                              void* d_out, int out_size, void* d_ws, size_t ws_size,
                              hipStream_t stream)
{
    const float* x      = (const float*)d_in[0];   // [4][512][2048]
    const float* w_qkv  = (const float*)d_in[1];   // [1536][512]
    const float* w_proj = (const float*)d_in[2];   // [512][512]
    const float* b_proj = (const float*)d_in[3];   // [512]
    float* out = (float*)d_out;                    // [4][512][2048]
    float* ws  = (float*)d_ws;

    float* qkv   = ws;                                         // 4*1536*2048
    float* cvals = qkv + (size_t)NB * (3 * CDIM) * SEQ;        // 4*8*2048
    float* aout  = cvals + (size_t)NB * NHEAD * SEQ;           // 4*512*2048

    dim3 blk(256);
    // qkv = w_qkv @ x   (per batch)
    gemm128<false><<<dim3(SEQ / 128, (3 * CDIM) / 128, NB), blk, 0, stream>>>(
        w_qkv, x, qkv, nullptr, 3 * CDIM, SEQ, CDIM);
    // softmax row constants
    attn_pass1<<<dim3(SEQ / 64, NB * NHEAD), blk, 0, stream>>>(qkv, cvals);
    // attention output
    attn_pass2<<<dim3(SEQ / 64, NB * NHEAD), blk, 0, stream>>>(qkv, cvals, aout);
    // out = w_proj @ aout + b_proj
    gemm128<true><<<dim3(SEQ / 128, CDIM / 128, NB), blk, 0, stream>>>(
        w_proj, aout, out, b_proj, CDIM, SEQ, CDIM);
}

// Round 2
// 519.340 us; speedup vs baseline: 1.8789x; 1.8789x over previous
//
#include <hip/hip_runtime.h>
#include <hip/hip_bf16.h>
#include <math.h>

#define SEQ   2048
#define NB    4
#define CDIM  512
#define NHEAD 8
#define HD    64
// scale * log2(e): softmax computed in exp2/log2 domain throughout
#define SL    (0.125f * 1.4426950408889634f)

typedef __attribute__((ext_vector_type(8))) short short8;
typedef __attribute__((ext_vector_type(4))) float f32x4;

__device__ inline f32x4 mfma16(short8 a, short8 b, f32x4 c) {
    return __builtin_amdgcn_mfma_f32_16x16x32_bf16(a, b, c, 0, 0, 0);
}

__device__ inline ushort bf16_rne(float f) {
    union { float f; unsigned u; } c; c.f = f;
    unsigned u = c.u + 0x7fffu + ((c.u >> 16) & 1u);
    return (ushort)(u >> 16);
}
__device__ inline float bf16_to_f(ushort h) {
    union { unsigned u; float f; } c; c.u = ((unsigned)h) << 16;
    return c.f;
}

// Universal LDS tile layout: [64 rows][64 cols bf16] = 128B pitch.
// Swizzle XORs byte bits [6:4] with (row&7)^((row>>3)&7):
//  - ds_read_b128 frag reads (16 lanes @ stride 128B) spread across banks
//  - transpose-scatter b16 writes (row varies by tid>>3) also spread.
__device__ inline int swz_off(int row, int byte_in_row) {
    return row * 128 + (byte_in_row ^ ((((row & 7) ^ ((row >> 3) & 7))) << 4));
}

// read an 8-bf16 MFMA fragment: row = (lane&15 [+16*frag]), kbyte = k2*64 + (lane>>4)*16
__device__ inline short8 frag(const ushort* base, int row, int kbyte) {
    return *(const short8*)(base + (swz_off(row, kbyte) >> 1));
}

// transpose-stage: global [64 d rows, stride SEQ] x 64 cols -> LDS [col][d] (swizzled)
__device__ inline void stage_T(ushort* dH, ushort* dL,
                               const ushort* sH, const ushort* sL,
                               int col0, int tid) {
    #pragma unroll
    for (int s = 0; s < 2; ++s) {
        int d  = (tid >> 3) + 32 * s;
        int ib = (tid & 7) * 8;
        short8 hv = *(const short8*)(sH + (size_t)d * SEQ + col0 + ib);
        short8 lv = *(const short8*)(sL + (size_t)d * SEQ + col0 + ib);
        #pragma unroll
        for (int e = 0; e < 8; ++e) {
            int off = swz_off(ib + e, d * 2) >> 1;
            dH[off] = (ushort)hv[e];
            dL[off] = (ushort)lv[e];
        }
    }
}

// direct-stage (no transpose): global [64 rows, stride SEQ] -> LDS [row][col] (swizzled)
__device__ inline void stage_D(ushort* dH, ushort* dL,
                               const ushort* sH, const ushort* sL,
                               int col0, int tid) {
    #pragma unroll
    for (int s = 0; s < 2; ++s) {
        int d  = (tid >> 3) + 32 * s;
        int ib = (tid & 7) * 8;
        short8 hv = *(const short8*)(sH + (size_t)d * SEQ + col0 + ib);
        short8 lv = *(const short8*)(sL + (size_t)d * SEQ + col0 + ib);
        int off = swz_off(d, ib * 2) >> 1;
        *(short8*)(dH + off) = hv;
        *(short8*)(dL + off) = lv;
    }
}

// ---------------------------------------------------------------------------
// fp32 GEMM 128x128x16, 256 thr, 8x8/thread.
// OMODE 0: fp32 out; 1: fp32 out + bias; 2: split bf16 hi/lo out.
// ---------------------------------------------------------------------------
template<int OMODE>
__global__ __launch_bounds__(256)
void gemm128(const float* __restrict__ A, const float* __restrict__ B,
             float* __restrict__ C, ushort* __restrict__ Ch, ushort* __restrict__ Cl,
             const float* __restrict__ bias, int M, int N, int K)
{
    const int bn  = blockIdx.x * 128;
    const int bm  = blockIdx.y * 128;
    const int bat = blockIdx.z;
    const float* Bp = B + (size_t)bat * K * N;

    __shared__ __align__(16) float As[16][128];
    __shared__ __align__(16) float Bs[16][128];

    const int tid = threadIdx.x;
    const int tm  = (tid >> 4) << 3;
    const int tn  = (tid & 15) << 3;

    float acc[8][8] = {};

    for (int k0 = 0; k0 < K; k0 += 16) {
        #pragma unroll
        for (int s = 0; s < 2; ++s) {
            int f4 = tid * 2 + s;
            int m  = f4 >> 2;
            int kc = (f4 & 3) << 2;
            float4 a = *(const float4*)(A + (size_t)(bm + m) * K + k0 + kc);
            As[kc + 0][m] = a.x; As[kc + 1][m] = a.y;
            As[kc + 2][m] = a.z; As[kc + 3][m] = a.w;
        }
        #pragma unroll
        for (int s = 0; s < 2; ++s) {
            int f4 = tid * 2 + s;
            int kk = f4 >> 5;
            int n  = (f4 & 31) << 2;
            *(float4*)&Bs[kk][n] =
                *(const float4*)(Bp + (size_t)(k0 + kk) * N + bn + n);
        }
        __syncthreads();
        #pragma unroll
        for (int kk = 0; kk < 16; ++kk) {
            float4 a0 = *(const float4*)&As[kk][tm];
            float4 a1 = *(const float4*)&As[kk][tm + 4];
            float4 b0 = *(const float4*)&Bs[kk][tn];
            float4 b1 = *(const float4*)&Bs[kk][tn + 4];
            float av[8] = {a0.x, a0.y, a0.z, a0.w, a1.x, a1.y, a1.z, a1.w};
            float bv[8] = {b0.x, b0.y, b0.z, b0.w, b1.x, b1.y, b1.z, b1.w};
            #pragma unroll
            for (int i = 0; i < 8; ++i)
                #pragma unroll
                for (int j = 0; j < 8; ++j)
                    acc[i][j] = fmaf(av[i], bv[j], acc[i][j]);
        }
        __syncthreads();
    }

    #pragma unroll
    for (int i = 0; i < 8; ++i) {
        if (OMODE == 2) {
            short8 hv, lv;
            #pragma unroll
            for (int j = 0; j < 8; ++j) {
                ushort h = bf16_rne(acc[i][j]);
                ushort l = bf16_rne(acc[i][j] - bf16_to_f(h));
                hv[j] = (short)h; lv[j] = (short)l;
            }
            size_t idx = (size_t)bat * M * N + (size_t)(bm + tm + i) * N + bn + tn;
            *(short8*)(Ch + idx) = hv;
            *(short8*)(Cl + idx) = lv;
        } else {
            float bi = (OMODE == 1) ? bias[bm + tm + i] : 0.0f;
            #pragma unroll
            for (int j = 0; j < 8; ++j) acc[i][j] += bi;
            float* row = C + (size_t)bat * M * N + (size_t)(bm + tm + i) * N + bn + tn;
            *(float4*)(row + 0) = make_float4(acc[i][0], acc[i][1], acc[i][2], acc[i][3]);
            *(float4*)(row + 4) = make_float4(acc[i][4], acc[i][5], acc[i][6], acc[i][7]);
        }
    }
}

// ---------------------------------------------------------------------------
// Pass 1 (MFMA, bf16x3 split): c_i = log2 sum_j 2^(S_ij*SL), S = K^T Q over d=64.
// Block: 64-key i-tile, 4 waves each owning a 16-query j-slice, loop j chunks.
// ---------------------------------------------------------------------------
__global__ __launch_bounds__(256)
void attn_pass1(const ushort* __restrict__ qkvh, const ushort* __restrict__ qkvl,
                float* __restrict__ cvals)
{
    const int it = blockIdx.x, bh = blockIdx.y;
    const int b = bh >> 3, h = bh & 7;
    const size_t base = ((size_t)b * (3 * CDIM) + h * 192) * SEQ;
    const ushort* qh_ = qkvh + base;
    const ushort* ql_ = qkvl + base;
    const ushort* kh_ = qh_ + (size_t)64 * SEQ;
    const ushort* kl_ = ql_ + (size_t)64 * SEQ;
    const int i0 = it * 64;

    __shared__ ushort KtH[4096], KtL[4096];
    __shared__ ushort QtH[4096], QtL[4096];
    __shared__ float red[4][64];

    const int tid = threadIdx.x;
    const int w = tid >> 6, lane = tid & 63, l15 = lane & 15, g = lane >> 4;

    stage_T(KtH, KtL, kh_, kl_, i0, tid);   // K^T tile: rows=i, cols=d

    float lsum[4][4] = {};                  // [i-frag][reg]
    const int jrow = 16 * w + l15;

    for (int jt = 0; jt < 32; ++jt) {
        __syncthreads();
        stage_T(QtH, QtL, qh_, ql_, jt * 64, tid);   // Q^T tile: rows=j, cols=d
        __syncthreads();

        short8 qbh0 = frag(QtH, jrow, g * 16), qbh1 = frag(QtH, jrow, 64 + g * 16);
        short8 qbl0 = frag(QtL, jrow, g * 16), qbl1 = frag(QtL, jrow, 64 + g * 16);

        #pragma unroll
        for (int mf = 0; mf < 4; ++mf) {
            const int arow = 16 * mf + l15;
            short8 ah0 = frag(KtH, arow, g * 16), ah1 = frag(KtH, arow, 64 + g * 16);
            short8 al0 = frag(KtL, arow, g * 16), al1 = frag(KtL, arow, 64 + g * 16);
            f32x4 sacc = {0.f, 0.f, 0.f, 0.f};
            sacc = mfma16(ah0, qbh0, sacc);
            sacc = mfma16(ah0, qbl0, sacc);
            sacc = mfma16(al0, qbh0, sacc);
            sacc = mfma16(ah1, qbh1, sacc);
            sacc = mfma16(ah1, qbl1, sacc);
            sacc = mfma16(al1, qbh1, sacc);
            #pragma unroll
            for (int r = 0; r < 4; ++r)
                lsum[mf][r] += exp2f(sacc[r] * SL);
        }
    }

    // reduce over the 16 j-lanes within each lane group
    #pragma unroll
    for (int mf = 0; mf < 4; ++mf)
        #pragma unroll
        for (int r = 0; r < 4; ++r) {
            float v = lsum[mf][r];
            v += __shfl_xor(v, 1); v += __shfl_xor(v, 2);
            v += __shfl_xor(v, 4); v += __shfl_xor(v, 8);
            lsum[mf][r] = v;
        }
    __syncthreads();
    if (l15 == 0) {
        #pragma unroll
        for (int mf = 0; mf < 4; ++mf)
            #pragma unroll
            for (int r = 0; r < 4; ++r)
                red[w][16 * mf + 4 * g + r] = lsum[mf][r];
    }
    __syncthreads();
    if (tid < 64) {
        float s = red[0][tid] + red[1][tid] + red[2][tid] + red[3][tid];
        cvals[(size_t)bh * SEQ + i0 + tid] = log2f(s);
    }
}

// ---------------------------------------------------------------------------
// Pass 2 (MFMA, bf16x3 split): out[d,j] = sum_i V[d,i] * 2^(S_ij*SL - c_i).
// Block: 64-query j-tile, loop 64-key i-chunks. Wave-private P strips.
// ---------------------------------------------------------------------------
__global__ __launch_bounds__(256)
void attn_pass2(const ushort* __restrict__ qkvh, const ushort* __restrict__ qkvl,
                const float* __restrict__ cvals, float* __restrict__ aout)
{
    const int jt = blockIdx.x, bh = blockIdx.y;
    const int b = bh >> 3, h = bh & 7;
    const size_t base = ((size_t)b * (3 * CDIM) + h * 192) * SEQ;
    const ushort* qh_ = qkvh + base;
    const ushort* ql_ = qkvl + base;
    const ushort* kh_ = qh_ + (size_t)64 * SEQ;
    const ushort* kl_ = ql_ + (size_t)64 * SEQ;
    const ushort* vh_ = qh_ + (size_t)128 * SEQ;
    const ushort* vl_ = ql_ + (size_t)128 * SEQ;
    float* ob = aout + ((size_t)b * CDIM + h * HD) * SEQ;
    const int j0 = jt * 64;

    __shared__ ushort QtH[4096], QtL[4096];
    __shared__ ushort KtH[4096], KtL[4096];
    __shared__ ushort VtH[4096], VtL[4096];
    __shared__ ushort PtH[4096], PtL[4096];

    const int tid = threadIdx.x;
    const int w = tid >> 6, lane = tid & 63, l15 = lane & 15, g = lane >> 4;
    const int jrow = 16 * w + l15;

    stage_T(QtH, QtL, qh_, ql_, j0, tid);   // rows=j, cols=d

    f32x4 oacc[4] = {};

    for (int ic = 0; ic < 32; ++ic) {
        const int i0 = ic * 64;
        __syncthreads();                    // protect Kt/Vt from prev-chunk readers
        stage_T(KtH, KtL, kh_, kl_, i0, tid);   // rows=i, cols=d
        stage_D(VtH, VtL, vh_, vl_, i0, tid);   // rows=d, cols=i
        __syncthreads();

        const float cv = cvals[(size_t)bh * SEQ + i0 + lane];

        short8 qbh0 = frag(QtH, jrow, g * 16), qbh1 = frag(QtH, jrow, 64 + g * 16);
        short8 qbl0 = frag(QtL, jrow, g * 16), qbl1 = frag(QtL, jrow, 64 + g * 16);

        // S tile + P write (wave-private 16 j-rows of Pt)
        #pragma unroll
        for (int mf = 0; mf < 4; ++mf) {
            const int arow = 16 * mf + l15;
            short8 ah0 = frag(KtH, arow, g * 16), ah1 = frag(KtH, arow, 64 + g * 16);
            short8 al0 = frag(KtL, arow, g * 16), al1 = frag(KtL, arow, 64 + g * 16);
            f32x4 sacc = {0.f, 0.f, 0.f, 0.f};
            sacc = mfma16(ah0, qbh0, sacc);
            sacc = mfma16(ah0, qbl0, sacc);
            sacc = mfma16(al0, qbh0, sacc);
            sacc = mfma16(ah1, qbh1, sacc);
            sacc = mfma16(ah1, qbl1, sacc);
            sacc = mfma16(al1, qbh1, sacc);
            #pragma unroll
            for (int r = 0; r < 4; ++r) {
                const int irow = 16 * mf + 4 * g + r;
                float c = __shfl(cv, irow);
                float p = exp2f(sacc[r] * SL - c);
                ushort ph = bf16_rne(p);
                ushort pl = bf16_rne(p - bf16_to_f(ph));
                int off = swz_off(jrow, irow * 2) >> 1;
                PtH[off] = ph;
                PtL[off] = pl;
            }
        }

        // PV: B-frags from wave-private Pt rows; A-frags from Vt
        short8 pbh0 = frag(PtH, jrow, g * 16), pbh1 = frag(PtH, jrow, 64 + g * 16);
        short8 pbl0 = frag(PtL, jrow, g * 16), pbl1 = frag(PtL, jrow, 64 + g * 16);
        #pragma unroll
        for (int mf = 0; mf < 4; ++mf) {
            const int vrow = 16 * mf + l15;
            short8 vh0 = frag(VtH, vrow, g * 16), vh1 = frag(VtH, vrow, 64 + g * 16);
            short8 vl0 = frag(VtL, vrow, g * 16), vl1 = frag(VtL, vrow, 64 + g * 16);
            oacc[mf] = mfma16(vh0, pbh0, oacc[mf]);
            oacc[mf] = mfma16(vh0, pbl0, oacc[mf]);
            oacc[mf] = mfma16(vl0, pbh0, oacc[mf]);
            oacc[mf] = mfma16(vh1, pbh1, oacc[mf]);
            oacc[mf] = mfma16(vh1, pbl1, oacc[mf]);
            oacc[mf] = mfma16(vl1, pbh1, oacc[mf]);
        }
    }

    #pragma unroll
    for (int mf = 0; mf < 4; ++mf)
        #pragma unroll
        for (int r = 0; r < 4; ++r) {
            int d = 16 * mf + 4 * g + r;
            ob[(size_t)d * SEQ + j0 + jrow] = oacc[mf][r];
        }
}

// ---------------------------------------------------------------------------
extern "C" void kernel_launch(void* const* d_in, const int* in_sizes, int n_in,
                              void* d_out, int out_size, void* d_ws, size_t ws_size,
                              hipStream_t stream)
{
    const float* x      = (const float*)d_in[0];   // [4][512][2048]
    const float* w_qkv  = (const float*)d_in[1];   // [1536][512]
    const float* w_proj = (const float*)d_in[2];   // [512][512]
    const float* b_proj = (const float*)d_in[3];   // [512]
    float* out = (float*)d_out;                    // [4][512][2048]

    ushort* qkvh = (ushort*)d_ws;                              // 4*1536*2048 bf16
    ushort* qkvl = qkvh + (size_t)NB * (3 * CDIM) * SEQ;       // 4*1536*2048 bf16
    float*  cvals = (float*)(qkvl + (size_t)NB * (3 * CDIM) * SEQ); // 4*8*2048 f32
    float*  aout  = cvals + (size_t)NB * NHEAD * SEQ;          // 4*512*2048 f32

    dim3 blk(256);
    // qkv = w_qkv @ x, written directly as bf16 hi/lo split
    gemm128<2><<<dim3(SEQ / 128, (3 * CDIM) / 128, NB), blk, 0, stream>>>(
        w_qkv, x, nullptr, qkvh, qkvl, nullptr, 3 * CDIM, SEQ, CDIM);
    // softmax row constants (log2 domain)
    attn_pass1<<<dim3(SEQ / 64, NB * NHEAD), blk, 0, stream>>>(qkvh, qkvl, cvals);
    // attention output
    attn_pass2<<<dim3(SEQ / 64, NB * NHEAD), blk, 0, stream>>>(qkvh, qkvl, cvals, aout);
    // out = w_proj @ aout + b_proj (fp32 vector GEMM)
    gemm128<1><<<dim3(SEQ / 128, CDIM / 128, NB), blk, 0, stream>>>(
        w_proj, aout, out, nullptr, nullptr, b_proj, CDIM, SEQ, CDIM);
}

// Round 3
// 358.496 us; speedup vs baseline: 2.7219x; 1.4487x over previous
//
#include <hip/hip_runtime.h>
#include <hip/hip_bf16.h>
#include <math.h>

#define SEQ   2048
#define NB    4
#define CDIM  512
#define NHEAD 8
#define HD    64
// scale * log2(e): folded into K channels at the qkv GEMM epilogue
#define SL    (0.125f * 1.4426950408889634f)

typedef __attribute__((ext_vector_type(8))) _Float16 f16x8;
typedef __attribute__((ext_vector_type(4))) _Float16 f16x4;
typedef __attribute__((ext_vector_type(4))) float f32x4;

__device__ inline f32x4 mfmaH(f16x8 a, f16x8 b, f32x4 c) {
    return __builtin_amdgcn_mfma_f32_16x16x32_f16(a, b, c, 0, 0, 0);
}

// Universal LDS tile layout: [64 rows][64 f16 cols] = 128B pitch.
// XOR byte bits [6:4] with (row&7)^((row>>3)&7): conflict-free b128 frag
// reads (16 lanes @ 128B stride) and near-free staging writes.
__device__ inline int swz_off(int row, int byte_in_row) {
    return row * 128 + (byte_in_row ^ ((((row & 7) ^ ((row >> 3) & 7))) << 4));
}

// read an 8-f16 MFMA fragment: row in tile, kbyte = khalf*64 + (lane>>4)*16
__device__ inline f16x8 fragH(const _Float16* base, int row, int kbyte) {
    return *(const f16x8*)(base + (swz_off(row, kbyte) >> 1));
}

// linear stage: one 64x64 f16 tile; src row pitch = spitch elems.
// thread t copies 16 f16 (32B) : row = t>>2, chunk = t&3.
__device__ inline void stage64(_Float16* dst, const _Float16* src, int spitch, int tid) {
    int row = tid >> 2, q = tid & 3;
    const _Float16* s = src + (size_t)row * spitch + q * 16;
    f16x8 a = *(const f16x8*)(s);
    f16x8 b = *(const f16x8*)(s + 8);
    *(f16x8*)(dst + (swz_off(row, q * 32) >> 1))      = a;
    *(f16x8*)(dst + (swz_off(row, q * 32 + 16) >> 1)) = b;
}

// ---------------------------------------------------------------------------
// fp32 GEMM 128x128x16, 256 thr, 8x8/thread.
// OMODE 1: fp32 out + bias (proj). OMODE 3: qkv writer -> q,k transposed fp16
// (K pre-scaled by SL) + v fp32 rows.
// ---------------------------------------------------------------------------
template<int OMODE>
__global__ __launch_bounds__(256)
void gemm128(const float* __restrict__ A, const float* __restrict__ B,
             float* __restrict__ C, _Float16* __restrict__ qkT,
             float* __restrict__ vf32, const float* __restrict__ bias,
             int M, int N, int K)
{
    const int bn  = blockIdx.x * 128;
    const int bm  = blockIdx.y * 128;
    const int bat = blockIdx.z;
    const float* Bp = B + (size_t)bat * K * N;

    __shared__ __align__(16) float As[16][128];
    __shared__ __align__(16) float Bs[16][128];

    const int tid = threadIdx.x;
    const int tm  = (tid >> 4) << 3;
    const int tn  = (tid & 15) << 3;

    float acc[8][8] = {};

    for (int k0 = 0; k0 < K; k0 += 16) {
        #pragma unroll
        for (int s = 0; s < 2; ++s) {
            int f4 = tid * 2 + s;
            int m  = f4 >> 2;
            int kc = (f4 & 3) << 2;
            float4 a = *(const float4*)(A + (size_t)(bm + m) * K + k0 + kc);
            As[kc + 0][m] = a.x; As[kc + 1][m] = a.y;
            As[kc + 2][m] = a.z; As[kc + 3][m] = a.w;
        }
        #pragma unroll
        for (int s = 0; s < 2; ++s) {
            int f4 = tid * 2 + s;
            int kk = f4 >> 5;
            int n  = (f4 & 31) << 2;
            *(float4*)&Bs[kk][n] =
                *(const float4*)(Bp + (size_t)(k0 + kk) * N + bn + n);
        }
        __syncthreads();
        #pragma unroll
        for (int kk = 0; kk < 16; ++kk) {
            float4 a0 = *(const float4*)&As[kk][tm];
            float4 a1 = *(const float4*)&As[kk][tm + 4];
            float4 b0 = *(const float4*)&Bs[kk][tn];
            float4 b1 = *(const float4*)&Bs[kk][tn + 4];
            float av[8] = {a0.x, a0.y, a0.z, a0.w, a1.x, a1.y, a1.z, a1.w};
            float bv[8] = {b0.x, b0.y, b0.z, b0.w, b1.x, b1.y, b1.z, b1.w};
            #pragma unroll
            for (int i = 0; i < 8; ++i)
                #pragma unroll
                for (int j = 0; j < 8; ++j)
                    acc[i][j] = fmaf(av[i], bv[j], acc[i][j]);
        }
        __syncthreads();
    }

    if (OMODE == 3) {
        const int o0 = bm + tm;            // first of this thread's 8 channels
        const int h  = o0 / 192;           // head (uniform per thread)
        const int r  = o0 % 192;           // channel within head triple
        if (r < 128) {
            // q (r<64, scale 1) or k (64..127, scale SL): transposed fp16
            const float sc = (r < 64) ? 1.0f : SL;
            _Float16* base = qkT + ((size_t)(bat * NHEAD + h) * SEQ) * 128 + r;
            #pragma unroll
            for (int j = 0; j < 8; ++j) {
                f16x8 hv;
                #pragma unroll
                for (int i = 0; i < 8; ++i) hv[i] = (_Float16)(acc[i][j] * sc);
                *(f16x8*)(base + (size_t)(bn + tn + j) * 128) = hv;
            }
        } else {
            const int d = r - 128;         // v channel
            float* vb = vf32 + ((size_t)(bat * NHEAD + h) * HD + d) * SEQ + bn + tn;
            #pragma unroll
            for (int i = 0; i < 8; ++i) {
                *(float4*)(vb + (size_t)i * SEQ + 0) =
                    make_float4(acc[i][0], acc[i][1], acc[i][2], acc[i][3]);
                *(float4*)(vb + (size_t)i * SEQ + 4) =
                    make_float4(acc[i][4], acc[i][5], acc[i][6], acc[i][7]);
            }
        }
    } else {
        #pragma unroll
        for (int i = 0; i < 8; ++i) {
            float bi = bias[bm + tm + i];
            #pragma unroll
            for (int j = 0; j < 8; ++j) acc[i][j] += bi;
            float* row = C + (size_t)bat * M * N + (size_t)(bm + tm + i) * N + bn + tn;
            *(float4*)(row + 0) = make_float4(acc[i][0], acc[i][1], acc[i][2], acc[i][3]);
            *(float4*)(row + 4) = make_float4(acc[i][4], acc[i][5], acc[i][6], acc[i][7]);
        }
    }
}

// ---------------------------------------------------------------------------
// Pass 1: c_i = log2 sum_j 2^(S_ij), S = K'^T Q over d=64 (SL pre-folded in K).
// Block: 64-key i-tile; 4 waves each own a 16-query j-slice; loop j chunks.
// K-frags hoisted in registers for the whole kernel.
// ---------------------------------------------------------------------------
__global__ __launch_bounds__(256)
void attn_pass1(const _Float16* __restrict__ qkT, float* __restrict__ cvals)
{
    const int it = blockIdx.x, bh = blockIdx.y;
    const _Float16* tb = qkT + ((size_t)bh * SEQ) * 128;
    const int i0 = it * 64;

    __shared__ __align__(16) _Float16 Kt[4096];
    __shared__ __align__(16) _Float16 Qt[4096];
    __shared__ float red[4][64];

    const int tid = threadIdx.x;
    const int w = tid >> 6, lane = tid & 63, l15 = lane & 15, g = lane >> 4;
    const int jrow = 16 * w + l15;

    stage64(Kt, tb + (size_t)i0 * 128 + 64, 128, tid);   // K cols 64..127
    __syncthreads();

    f16x8 kf[4][2];
    #pragma unroll
    for (int mf = 0; mf < 4; ++mf) {
        kf[mf][0] = fragH(Kt, 16 * mf + l15, g * 16);
        kf[mf][1] = fragH(Kt, 16 * mf + l15, 64 + g * 16);
    }

    float lsum[4][4] = {};

    for (int jt = 0; jt < 32; ++jt) {
        __syncthreads();
        stage64(Qt, tb + (size_t)(jt * 64) * 128, 128, tid);   // Q cols 0..63
        __syncthreads();

        f16x8 qb0 = fragH(Qt, jrow, g * 16);
        f16x8 qb1 = fragH(Qt, jrow, 64 + g * 16);

        #pragma unroll
        for (int mf = 0; mf < 4; ++mf) {
            f32x4 s = {0.f, 0.f, 0.f, 0.f};
            s = mfmaH(kf[mf][0], qb0, s);
            s = mfmaH(kf[mf][1], qb1, s);
            #pragma unroll
            for (int r = 0; r < 4; ++r)
                lsum[mf][r] += exp2f(s[r]);
        }
    }

    #pragma unroll
    for (int mf = 0; mf < 4; ++mf)
        #pragma unroll
        for (int r = 0; r < 4; ++r) {
            float v = lsum[mf][r];
            v += __shfl_xor(v, 1); v += __shfl_xor(v, 2);
            v += __shfl_xor(v, 4); v += __shfl_xor(v, 8);
            lsum[mf][r] = v;
        }
    __syncthreads();
    if (l15 == 0) {
        #pragma unroll
        for (int mf = 0; mf < 4; ++mf)
            #pragma unroll
            for (int r = 0; r < 4; ++r)
                red[w][16 * mf + 4 * g + r] = lsum[mf][r];
    }
    __syncthreads();
    if (tid < 64) {
        float s = red[0][tid] + red[1][tid] + red[2][tid] + red[3][tid];
        cvals[(size_t)bh * SEQ + i0 + tid] = log2f(s);
    }
}

// ---------------------------------------------------------------------------
// Pass 1b: V'' = v * 2^(-c_i/2) -> fp16. 8 elems/thread, fully coalesced.
// ---------------------------------------------------------------------------
__global__ __launch_bounds__(256)
void prescale_v(const float* __restrict__ vf32, const float* __restrict__ cvals,
                _Float16* __restrict__ vf16)
{
    const size_t e0 = ((size_t)blockIdx.x * 256 + threadIdx.x) * 8;
    const int bh = (int)(e0 / ((size_t)HD * SEQ));
    const size_t rem = e0 % ((size_t)HD * SEQ);
    const int n = (int)(rem % SEQ);

    const float* cp = cvals + (size_t)bh * SEQ + n;
    const float* vp = vf32 + e0;
    f16x8 o;
    #pragma unroll
    for (int k = 0; k < 8; ++k)
        o[k] = (_Float16)(vp[k] * exp2f(-0.5f * cp[k]));
    *(f16x8*)(vf16 + e0) = o;
}

// ---------------------------------------------------------------------------
// Pass 2: out[d,j] = sum_i V''[d,i] * 2^(S_ij - c_i/2).
// Block: 64-query j-tile; loop 64-key i-chunks. Q-frags hoisted; P packed b64.
// ---------------------------------------------------------------------------
__global__ __launch_bounds__(256)
void attn_pass2(const _Float16* __restrict__ qkT, const _Float16* __restrict__ vf16,
                const float* __restrict__ cvals, float* __restrict__ aout)
{
    const int jt = blockIdx.x, bh = blockIdx.y;
    const int b = bh >> 3, h = bh & 7;
    const _Float16* tb = qkT + ((size_t)bh * SEQ) * 128;
    const _Float16* vb = vf16 + ((size_t)bh * HD) * SEQ;
    float* ob = aout + ((size_t)b * CDIM + h * HD) * SEQ;
    const int j0 = jt * 64;

    __shared__ __align__(16) _Float16 Qt[4096];
    __shared__ __align__(16) _Float16 Kt[4096];
    __shared__ __align__(16) _Float16 Vt[4096];
    __shared__ __align__(16) _Float16 Pt[4096];

    const int tid = threadIdx.x;
    const int w = tid >> 6, lane = tid & 63, l15 = lane & 15, g = lane >> 4;
    const int jrow = 16 * w + l15;

    stage64(Qt, tb + (size_t)j0 * 128, 128, tid);   // Q cols 0..63
    __syncthreads();
    const f16x8 qb0 = fragH(Qt, jrow, g * 16);
    const f16x8 qb1 = fragH(Qt, jrow, 64 + g * 16);

    f32x4 oacc[4] = {};

    for (int ic = 0; ic < 32; ++ic) {
        const int i0 = ic * 64;
        __syncthreads();                 // prev-iter Kt/Vt/Pt readers done
        stage64(Kt, tb + (size_t)i0 * 128 + 64, 128, tid);
        stage64(Vt, vb + i0, SEQ, tid);  // V''[d][i] rows=d
        const float cv = cvals[(size_t)bh * SEQ + i0 + lane];
        __syncthreads();

        // S tile + P = 2^(S - c/2), wave-private 16 j-rows of Pt
        #pragma unroll
        for (int mf = 0; mf < 4; ++mf) {
            f16x8 a0 = fragH(Kt, 16 * mf + l15, g * 16);
            f16x8 a1 = fragH(Kt, 16 * mf + l15, 64 + g * 16);
            f32x4 s = {0.f, 0.f, 0.f, 0.f};
            s = mfmaH(a0, qb0, s);
            s = mfmaH(a1, qb1, s);
            f16x4 pv;
            #pragma unroll
            for (int r = 0; r < 4; ++r) {
                const int irow = 16 * mf + 4 * g + r;
                float ch = 0.5f * __shfl(cv, irow);
                pv[r] = (_Float16)exp2f(s[r] - ch);
            }
            *(f16x4*)(Pt + (swz_off(jrow, (16 * mf + 4 * g) * 2) >> 1)) = pv;
        }

        // PV: B-frags from wave-private Pt rows; A-frags from Vt
        f16x8 pb0 = fragH(Pt, jrow, g * 16);
        f16x8 pb1 = fragH(Pt, jrow, 64 + g * 16);
        #pragma unroll
        for (int mf = 0; mf < 4; ++mf) {
            f16x8 v0 = fragH(Vt, 16 * mf + l15, g * 16);
            f16x8 v1 = fragH(Vt, 16 * mf + l15, 64 + g * 16);
            oacc[mf] = mfmaH(v0, pb0, oacc[mf]);
            oacc[mf] = mfmaH(v1, pb1, oacc[mf]);
        }
    }

    #pragma unroll
    for (int mf = 0; mf < 4; ++mf)
        #pragma unroll
        for (int r = 0; r < 4; ++r) {
            int d = 16 * mf + 4 * g + r;
            ob[(size_t)d * SEQ + j0 + jrow] = oacc[mf][r];
        }
}

// ---------------------------------------------------------------------------
extern "C" void kernel_launch(void* const* d_in, const int* in_sizes, int n_in,
                              void* d_out, int out_size, void* d_ws, size_t ws_size,
                              hipStream_t stream)
{
    const float* x      = (const float*)d_in[0];   // [4][512][2048]
    const float* w_qkv  = (const float*)d_in[1];   // [1536][512]
    const float* w_proj = (const float*)d_in[2];   // [512][512]
    const float* b_proj = (const float*)d_in[3];   // [512]
    float* out = (float*)d_out;                    // [4][512][2048]

    // workspace layout
    _Float16* qkT  = (_Float16*)d_ws;                             // 4*8*2048*128 f16
    _Float16* vf16 = qkT + (size_t)NB * NHEAD * SEQ * 128;        // 4*8*64*2048 f16
    float*    vf32 = (float*)(vf16 + (size_t)NB * NHEAD * HD * SEQ);  // same count f32
    float*    cvals = vf32 + (size_t)NB * NHEAD * HD * SEQ;       // 4*8*2048 f32
    float*    aout  = cvals + (size_t)NB * NHEAD * SEQ;           // 4*512*2048 f32

    dim3 blk(256);
    // qkv = w_qkv @ x; q,k -> transposed fp16 (K scaled by SL), v -> fp32 rows
    gemm128<3><<<dim3(SEQ / 128, (3 * CDIM) / 128, NB), blk, 0, stream>>>(
        w_qkv, x, nullptr, qkT, vf32, nullptr, 3 * CDIM, SEQ, CDIM);
    // softmax row constants (log2 domain)
    attn_pass1<<<dim3(SEQ / 64, NB * NHEAD), blk, 0, stream>>>(qkT, cvals);
    // V'' = v * 2^(-c/2) in fp16
    prescale_v<<<dim3((NB * NHEAD * HD * SEQ) / (256 * 8)), blk, 0, stream>>>(
        vf32, cvals, vf16);
    // attention output
    attn_pass2<<<dim3(SEQ / 64, NB * NHEAD), blk, 0, stream>>>(qkT, vf16, cvals, aout);
    // out = w_proj @ aout + b_proj (fp32 vector GEMM)
    gemm128<1><<<dim3(SEQ / 128, CDIM / 128, NB), blk, 0, stream>>>(
        w_proj, aout, out, nullptr, nullptr, b_proj, CDIM, SEQ, CDIM);
}

// Round 4
// 226.422 us; speedup vs baseline: 4.3097x; 1.5833x over previous
//
#include <hip/hip_runtime.h>
#include <hip/hip_bf16.h>
#include <math.h>

#define SEQ   2048
#define NB    4
#define CDIM  512
#define NHEAD 8
#define HD    64
// scale * log2(e): folded into K channels at the qkv GEMM epilogue
#define SL    (0.125f * 1.4426950408889634f)

typedef __attribute__((ext_vector_type(8))) short short8;
typedef __attribute__((ext_vector_type(8))) _Float16 f16x8;
typedef __attribute__((ext_vector_type(4))) _Float16 f16x4;
typedef __attribute__((ext_vector_type(4))) float f32x4;

__device__ inline f32x4 mfmaH(f16x8 a, f16x8 b, f32x4 c) {
    return __builtin_amdgcn_mfma_f32_16x16x32_f16(a, b, c, 0, 0, 0);
}
__device__ inline f32x4 mfmaB(short8 a, short8 b, f32x4 c) {
    return __builtin_amdgcn_mfma_f32_16x16x32_bf16(a, b, c, 0, 0, 0);
}

__device__ inline ushort bf16_rne(float f) {
    union { float f; unsigned u; } c; c.f = f;
    unsigned u = c.u + 0x7fffu + ((c.u >> 16) & 1u);
    return (ushort)(u >> 16);
}
__device__ inline float bf16_to_f(ushort h) {
    union { unsigned u; float f; } c; c.u = ((unsigned)h) << 16;
    return c.f;
}

// Universal LDS tile layout: [rows][64 cols of 2B] = 128B pitch.
// XOR byte bits [6:4] with (row&7)^((row>>3)&7): conflict-free b128 frag
// reads (16 lanes @ 128B stride) and near-free staging writes.
__device__ inline int swz_off(int row, int byte_in_row) {
    return row * 128 + (byte_in_row ^ ((((row & 7) ^ ((row >> 3) & 7))) << 4));
}

__device__ inline f16x8 fragH(const _Float16* base, int row, int kbyte) {
    return *(const f16x8*)(base + (swz_off(row, kbyte) >> 1));
}
__device__ inline short8 fragB(const ushort* base, int row, int kbyte) {
    return *(const short8*)(base + (swz_off(row, kbyte) >> 1));
}

// linear stage: 64x64 2B tile; src row pitch = spitch elems.
__device__ inline void stage64(_Float16* dst, const _Float16* src, int spitch, int tid) {
    int row = tid >> 2, q = tid & 3;
    const _Float16* s = src + (size_t)row * spitch + q * 16;
    f16x8 a = *(const f16x8*)(s);
    f16x8 b = *(const f16x8*)(s + 8);
    *(f16x8*)(dst + (swz_off(row, q * 32) >> 1))      = a;
    *(f16x8*)(dst + (swz_off(row, q * 32 + 16) >> 1)) = b;
}

// linear stage: 128x64 2B tile; src row pitch = 512 elems (K dim).
__device__ inline void stage128(ushort* dst, const ushort* src, int tid) {
    const int row = tid >> 1, half = tid & 1;
    const ushort* s = src + (size_t)row * 512 + half * 32;
    #pragma unroll
    for (int c = 0; c < 4; ++c) {
        short8 v = *(const short8*)(s + c * 8);
        *(short8*)(dst + (swz_off(row, half * 64 + c * 16) >> 1)) = v;
    }
}

// ---------------------------------------------------------------------------
// conv_w: split both weight matrices into bf16 hi/lo.
// ---------------------------------------------------------------------------
__global__ __launch_bounds__(256)
void conv_w(const float* __restrict__ w1, const float* __restrict__ w2,
            ushort* __restrict__ w1h, ushort* __restrict__ w1l,
            ushort* __restrict__ w2h, ushort* __restrict__ w2l)
{
    const size_t NW1 = (size_t)3 * CDIM * CDIM;
    size_t i = ((size_t)blockIdx.x * 256 + threadIdx.x) * 8;
    const float* src; ushort *dh, *dl;
    if (i < NW1) { src = w1 + i; dh = w1h + i; dl = w1l + i; }
    else { size_t j = i - NW1; src = w2 + j; dh = w2h + j; dl = w2l + j; }
    float4 a = *(const float4*)src, b = *(const float4*)(src + 4);
    float f[8] = {a.x, a.y, a.z, a.w, b.x, b.y, b.z, b.w};
    short8 hv, lv;
    #pragma unroll
    for (int e = 0; e < 8; ++e) {
        ushort hi = bf16_rne(f[e]);
        hv[e] = (short)hi;
        lv[e] = (short)bf16_rne(f[e] - bf16_to_f(hi));
    }
    *(short8*)dh = hv; *(short8*)dl = lv;
}

// ---------------------------------------------------------------------------
// conv_x: x[b][c][n] f32 -> xT[b][n][c] split bf16 hi/lo (LDS-tiled transpose)
// ---------------------------------------------------------------------------
__global__ __launch_bounds__(256)
void conv_x(const float* __restrict__ x, ushort* __restrict__ xh, ushort* __restrict__ xl)
{
    __shared__ float T[64][65];
    const int n0 = blockIdx.x * 64, c0 = blockIdx.y * 64, b = blockIdx.z;
    const int t = threadIdx.x, r = t >> 2, q = t & 3;
    const float* src = x + ((size_t)b * CDIM + c0 + r) * SEQ + n0 + q * 16;
    #pragma unroll
    for (int c = 0; c < 4; ++c) {
        float4 v = *(const float4*)(src + c * 4);
        T[r][q * 16 + c * 4 + 0] = v.x; T[r][q * 16 + c * 4 + 1] = v.y;
        T[r][q * 16 + c * 4 + 2] = v.z; T[r][q * 16 + c * 4 + 3] = v.w;
    }
    __syncthreads();
    short8 hv[2], lv[2];
    #pragma unroll
    for (int k = 0; k < 16; ++k) {
        float f = T[q * 16 + k][r];
        ushort hi = bf16_rne(f);
        hv[k >> 3][k & 7] = (short)hi;
        lv[k >> 3][k & 7] = (short)bf16_rne(f - bf16_to_f(hi));
    }
    size_t o = ((size_t)b * SEQ + n0 + r) * CDIM + c0 + q * 16;
    *(short8*)(xh + o) = hv[0]; *(short8*)(xh + o + 8) = hv[1];
    *(short8*)(xl + o) = lv[0]; *(short8*)(xl + o + 8) = lv[1];
}

// ---------------------------------------------------------------------------
// Split-bf16 MFMA GEMM: D[m][n] = sum_k A[m][k]*B[n][k], K=512, bf16x3.
// Block 128m x 128n, BK=64, 4 waves (2x2), 64x64 per wave.
// EPI 0 (qkv): m=seq, n=ch -> qkT[seq][128] fp16 (K scaled SL), vT[seq][64] fp16
// EPI 1 (proj): m=co, n=seq -> out[b][co][n] f32 + bias
// ---------------------------------------------------------------------------
template<int EPI>
__global__ __launch_bounds__(256)
void gemm_sp(const ushort* __restrict__ AH, const ushort* __restrict__ AL, size_t sA,
             const ushort* __restrict__ BH, const ushort* __restrict__ BL, size_t sB,
             _Float16* __restrict__ qkT, _Float16* __restrict__ vT,
             float* __restrict__ outp, const float* __restrict__ bias)
{
    const int bn = blockIdx.x * 128, bm = blockIdx.y * 128, bat = blockIdx.z;
    __shared__ __align__(16) ushort sAH[8192], sAL[8192], sBH[8192], sBL[8192];
    const int tid = threadIdx.x;
    const int w = tid >> 6, lane = tid & 63, l15 = lane & 15, g = lane >> 4;
    const int wm = w >> 1, wn = w & 1;
    const ushort* Ah = AH + sA * bat + (size_t)bm * 512;
    const ushort* Al = AL + sA * bat + (size_t)bm * 512;
    const ushort* Bh = BH + sB * bat + (size_t)bn * 512;
    const ushort* Bl = BL + sB * bat + (size_t)bn * 512;

    f32x4 acc[4][4] = {};

    for (int k0 = 0; k0 < 512; k0 += 64) {
        __syncthreads();
        stage128(sAH, Ah + k0, tid);
        stage128(sAL, Al + k0, tid);
        stage128(sBH, Bh + k0, tid);
        stage128(sBL, Bl + k0, tid);
        __syncthreads();
        #pragma unroll
        for (int kh = 0; kh < 2; ++kh) {
            short8 bh[4], bl[4];
            #pragma unroll
            for (int nf = 0; nf < 4; ++nf) {
                bh[nf] = fragB(sBH, 64 * wn + 16 * nf + l15, kh * 64 + g * 16);
                bl[nf] = fragB(sBL, 64 * wn + 16 * nf + l15, kh * 64 + g * 16);
            }
            #pragma unroll
            for (int mf = 0; mf < 4; ++mf) {
                short8 ah = fragB(sAH, 64 * wm + 16 * mf + l15, kh * 64 + g * 16);
                short8 al = fragB(sAL, 64 * wm + 16 * mf + l15, kh * 64 + g * 16);
                #pragma unroll
                for (int nf = 0; nf < 4; ++nf) {
                    acc[mf][nf] = mfmaB(ah, bh[nf], acc[mf][nf]);
                    acc[mf][nf] = mfmaB(ah, bl[nf], acc[mf][nf]);
                    acc[mf][nf] = mfmaB(al, bh[nf], acc[mf][nf]);
                }
            }
        }
    }

    if (EPI == 0) {
        #pragma unroll
        for (int nf = 0; nf < 4; ++nf) {
            const int c0 = bn + 64 * wn + 16 * nf;   // frag-uniform (16 | boundaries)
            const int h = c0 / 192, rr = c0 % 192;
            if (rr < 128) {
                const float sc = (rr < 64) ? 1.0f : SL;
                _Float16* base = qkT + ((size_t)(bat * NHEAD + h) * SEQ) * 128 + rr + l15;
                #pragma unroll
                for (int mf = 0; mf < 4; ++mf)
                    #pragma unroll
                    for (int r = 0; r < 4; ++r) {
                        const int sj = bm + 64 * wm + 16 * mf + 4 * g + r;
                        base[(size_t)sj * 128] = (_Float16)(acc[mf][nf][r] * sc);
                    }
            } else {
                _Float16* base = vT + ((size_t)(bat * NHEAD + h) * SEQ) * HD + (rr - 128) + l15;
                #pragma unroll
                for (int mf = 0; mf < 4; ++mf)
                    #pragma unroll
                    for (int r = 0; r < 4; ++r) {
                        const int sj = bm + 64 * wm + 16 * mf + 4 * g + r;
                        base[(size_t)sj * HD] = (_Float16)acc[mf][nf][r];
                    }
            }
        }
    } else {
        #pragma unroll
        for (int mf = 0; mf < 4; ++mf)
            #pragma unroll
            for (int r = 0; r < 4; ++r) {
                const int co = bm + 64 * wm + 16 * mf + 4 * g + r;
                const float bv = bias[co];
                float* base = outp + ((size_t)bat * CDIM + co) * SEQ + bn + 64 * wn + l15;
                #pragma unroll
                for (int nf = 0; nf < 4; ++nf)
                    base[16 * nf] = acc[mf][nf][r] + bv;
            }
    }
}

// ---------------------------------------------------------------------------
// Pass 1: c_i = log2 sum_j 2^(S_ij), S = K'^T Q over d=64 (SL pre-folded in K).
// ---------------------------------------------------------------------------
__global__ __launch_bounds__(256)
void attn_pass1(const _Float16* __restrict__ qkT, float* __restrict__ cvals)
{
    const int it = blockIdx.x, bh = blockIdx.y;
    const _Float16* tb = qkT + ((size_t)bh * SEQ) * 128;
    const int i0 = it * 64;

    __shared__ __align__(16) _Float16 Kt[4096];
    __shared__ __align__(16) _Float16 Qt[4096];
    __shared__ float red[4][64];

    const int tid = threadIdx.x;
    const int w = tid >> 6, lane = tid & 63, l15 = lane & 15, g = lane >> 4;
    const int jrow = 16 * w + l15;

    stage64(Kt, tb + (size_t)i0 * 128 + 64, 128, tid);   // K cols 64..127
    __syncthreads();

    f16x8 kf[4][2];
    #pragma unroll
    for (int mf = 0; mf < 4; ++mf) {
        kf[mf][0] = fragH(Kt, 16 * mf + l15, g * 16);
        kf[mf][1] = fragH(Kt, 16 * mf + l15, 64 + g * 16);
    }

    float lsum[4][4] = {};

    for (int jt = 0; jt < 32; ++jt) {
        __syncthreads();
        stage64(Qt, tb + (size_t)(jt * 64) * 128, 128, tid);   // Q cols 0..63
        __syncthreads();

        f16x8 qb0 = fragH(Qt, jrow, g * 16);
        f16x8 qb1 = fragH(Qt, jrow, 64 + g * 16);

        #pragma unroll
        for (int mf = 0; mf < 4; ++mf) {
            f32x4 s = {0.f, 0.f, 0.f, 0.f};
            s = mfmaH(kf[mf][0], qb0, s);
            s = mfmaH(kf[mf][1], qb1, s);
            #pragma unroll
            for (int r = 0; r < 4; ++r)
                lsum[mf][r] += exp2f(s[r]);
        }
    }

    #pragma unroll
    for (int mf = 0; mf < 4; ++mf)
        #pragma unroll
        for (int r = 0; r < 4; ++r) {
            float v = lsum[mf][r];
            v += __shfl_xor(v, 1); v += __shfl_xor(v, 2);
            v += __shfl_xor(v, 4); v += __shfl_xor(v, 8);
            lsum[mf][r] = v;
        }
    __syncthreads();
    if (l15 == 0) {
        #pragma unroll
        for (int mf = 0; mf < 4; ++mf)
            #pragma unroll
            for (int r = 0; r < 4; ++r)
                red[w][16 * mf + 4 * g + r] = lsum[mf][r];
    }
    __syncthreads();
    if (tid < 64) {
        float s = red[0][tid] + red[1][tid] + red[2][tid] + red[3][tid];
        cvals[(size_t)bh * SEQ + i0 + tid] = log2f(s);
    }
}

// ---------------------------------------------------------------------------
// prescale_v: vT[bh][i][d] f16 -> vf16[bh][d][i] f16, scaled by 2^(-c_i/2).
// LDS-tiled transpose (64x64 per block).
// ---------------------------------------------------------------------------
__global__ __launch_bounds__(256)
void prescale_v(const _Float16* __restrict__ vT, const float* __restrict__ cvals,
                _Float16* __restrict__ vf16)
{
    __shared__ float T[64][65];
    const int i0 = blockIdx.x * 64, bh = blockIdx.y;
    const int t = threadIdx.x, r = t >> 2, q = t & 3;
    const float cf = exp2f(-0.5f * cvals[(size_t)bh * SEQ + i0 + r]);
    const _Float16* src = vT + ((size_t)bh * SEQ + i0 + r) * HD + q * 16;
    f16x8 a = *(const f16x8*)src, b = *(const f16x8*)(src + 8);
    #pragma unroll
    for (int k = 0; k < 8; ++k) {
        T[r][q * 16 + k]     = (float)a[k] * cf;
        T[r][q * 16 + 8 + k] = (float)b[k] * cf;
    }
    __syncthreads();
    f16x8 o0, o1;
    #pragma unroll
    for (int k = 0; k < 8; ++k) {
        o0[k] = (_Float16)T[q * 16 + k][r];
        o1[k] = (_Float16)T[q * 16 + 8 + k][r];
    }
    _Float16* dst = vf16 + ((size_t)bh * HD + r) * SEQ + i0 + q * 16;
    *(f16x8*)dst = o0; *(f16x8*)(dst + 8) = o1;
}

// ---------------------------------------------------------------------------
// Pass 2: outT[j][d] = sum_i P^T[j][i] * V''^T[i][d], P = 2^(S - c/2).
// Emits aoutT[b][seq][512ch] as split bf16 hi/lo (proj GEMM B operand).
// ---------------------------------------------------------------------------
__global__ __launch_bounds__(256)
void attn_pass2(const _Float16* __restrict__ qkT, const _Float16* __restrict__ vf16,
                const float* __restrict__ cvals,
                ushort* __restrict__ aoth, ushort* __restrict__ aotl)
{
    const int jt = blockIdx.x, bh = blockIdx.y;
    const int b = bh >> 3, h = bh & 7;
    const _Float16* tb = qkT + ((size_t)bh * SEQ) * 128;
    const _Float16* vb = vf16 + ((size_t)bh * HD) * SEQ;
    const int j0 = jt * 64;

    __shared__ __align__(16) _Float16 Qt[4096];
    __shared__ __align__(16) _Float16 Kt[4096];
    __shared__ __align__(16) _Float16 Vt[4096];
    __shared__ __align__(16) _Float16 Pt[4096];

    const int tid = threadIdx.x;
    const int w = tid >> 6, lane = tid & 63, l15 = lane & 15, g = lane >> 4;
    const int jrow = 16 * w + l15;

    stage64(Qt, tb + (size_t)j0 * 128, 128, tid);   // Q cols 0..63
    __syncthreads();
    const f16x8 qb0 = fragH(Qt, jrow, g * 16);
    const f16x8 qb1 = fragH(Qt, jrow, 64 + g * 16);

    f32x4 oacc[4] = {};

    for (int ic = 0; ic < 32; ++ic) {
        const int i0 = ic * 64;
        __syncthreads();                 // prev-iter Kt/Vt/Pt readers done
        stage64(Kt, tb + (size_t)i0 * 128 + 64, 128, tid);
        stage64(Vt, vb + i0, SEQ, tid);  // V''[d][i] rows=d
        const float cv = cvals[(size_t)bh * SEQ + i0 + lane];
        __syncthreads();

        // S tile + P = 2^(S - c/2), wave-private 16 j-rows of Pt
        #pragma unroll
        for (int mf = 0; mf < 4; ++mf) {
            f16x8 a0 = fragH(Kt, 16 * mf + l15, g * 16);
            f16x8 a1 = fragH(Kt, 16 * mf + l15, 64 + g * 16);
            f32x4 s = {0.f, 0.f, 0.f, 0.f};
            s = mfmaH(a0, qb0, s);
            s = mfmaH(a1, qb1, s);
            f16x4 pv;
            #pragma unroll
            for (int r = 0; r < 4; ++r) {
                const int irow = 16 * mf + 4 * g + r;
                float ch = 0.5f * __shfl(cv, irow);
                pv[r] = (_Float16)exp2f(s[r] - ch);
            }
            *(f16x4*)(Pt + (swz_off(jrow, (16 * mf + 4 * g) * 2) >> 1)) = pv;
        }

        // PV with A=P (m=j), B=V (n=d): same LDS reads, D = outT fragment
        f16x8 pb0 = fragH(Pt, jrow, g * 16);
        f16x8 pb1 = fragH(Pt, jrow, 64 + g * 16);
        #pragma unroll
        for (int nf = 0; nf < 4; ++nf) {
            f16x8 v0 = fragH(Vt, 16 * nf + l15, g * 16);
            f16x8 v1 = fragH(Vt, 16 * nf + l15, 64 + g * 16);
            oacc[nf] = mfmaH(pb0, v0, oacc[nf]);
            oacc[nf] = mfmaH(pb1, v1, oacc[nf]);
        }
    }

    // write aoutT[j][h*64+d] split bf16: lane col d=l15 contiguous (32B segs)
    #pragma unroll
    for (int nf = 0; nf < 4; ++nf)
        #pragma unroll
        for (int r = 0; r < 4; ++r) {
            const int j = j0 + 16 * w + 4 * g + r;
            const int ch = h * HD + 16 * nf + l15;
            const size_t idx = ((size_t)b * SEQ + j) * CDIM + ch;
            float v = oacc[nf][r];
            ushort hi = bf16_rne(v);
            aoth[idx] = hi;
            aotl[idx] = bf16_rne(v - bf16_to_f(hi));
        }
}

// ---------------------------------------------------------------------------
extern "C" void kernel_launch(void* const* d_in, const int* in_sizes, int n_in,
                              void* d_out, int out_size, void* d_ws, size_t ws_size,
                              hipStream_t stream)
{
    const float* x      = (const float*)d_in[0];   // [4][512][2048]
    const float* w_qkv  = (const float*)d_in[1];   // [1536][512]
    const float* w_proj = (const float*)d_in[2];   // [512][512]
    const float* b_proj = (const float*)d_in[3];   // [512]
    float* out = (float*)d_out;                    // [4][512][2048]

    char* p = (char*)d_ws;
    auto alloc = [&](size_t bytes) { char* q = p; p += (bytes + 255) & ~(size_t)255; return q; };
    _Float16* qkT  = (_Float16*)alloc((size_t)NB * NHEAD * SEQ * 128 * 2); // 16 MB
    _Float16* vT   = (_Float16*)alloc((size_t)NB * NHEAD * SEQ * HD * 2);  // 8 MB
    float*    cvals = (float*)alloc((size_t)NB * NHEAD * SEQ * 4);         // 256 KB
    ushort*   xTh  = (ushort*)alloc((size_t)NB * SEQ * CDIM * 2);          // 8 MB
    ushort*   xTl  = (ushort*)alloc((size_t)NB * SEQ * CDIM * 2);          // 8 MB
    ushort*   wqh  = (ushort*)alloc((size_t)3 * CDIM * CDIM * 2);
    ushort*   wql  = (ushort*)alloc((size_t)3 * CDIM * CDIM * 2);
    ushort*   wph  = (ushort*)alloc((size_t)CDIM * CDIM * 2);
    ushort*   wpl  = (ushort*)alloc((size_t)CDIM * CDIM * 2);
    ushort*   aoth = (ushort*)alloc((size_t)NB * SEQ * CDIM * 2);          // 8 MB
    ushort*   aotl = (ushort*)alloc((size_t)NB * SEQ * CDIM * 2);          // 8 MB
    // vf16 aliases xTh: xT is dead after the qkv GEMM; prescale_v writes it
    // before attn_pass2 reads it (stream-ordered, deterministic each replay).
    _Float16* vf16 = (_Float16*)xTh;

    dim3 blk(256);
    // weight + input splits
    conv_w<<<dim3(512), blk, 0, stream>>>(w_qkv, w_proj, wqh, wql, wph, wpl);
    conv_x<<<dim3(SEQ / 64, CDIM / 64, NB), blk, 0, stream>>>(x, xTh, xTl);
    // qkv: D[seq][ch] -> qkT fp16 (K*SL) + vT fp16
    gemm_sp<0><<<dim3(12, 16, NB), blk, 0, stream>>>(
        xTh, xTl, (size_t)SEQ * CDIM, wqh, wql, 0,
        qkT, vT, nullptr, nullptr);
    // softmax row constants (log2 domain)
    attn_pass1<<<dim3(SEQ / 64, NB * NHEAD), blk, 0, stream>>>(qkT, cvals);
    // V'' = v * 2^(-c/2), transposed to [d][i] fp16
    prescale_v<<<dim3(SEQ / 64, NB * NHEAD), blk, 0, stream>>>(vT, cvals, vf16);
    // attention -> aoutT split bf16
    attn_pass2<<<dim3(SEQ / 64, NB * NHEAD), blk, 0, stream>>>(
        qkT, vf16, cvals, aoth, aotl);
    // proj: D[co][seq] = w_proj @ aout + bias
    gemm_sp<1><<<dim3(16, 4, NB), blk, 0, stream>>>(
        wph, wpl, 0, aoth, aotl, (size_t)SEQ * CDIM,
        nullptr, nullptr, out, b_proj);
}

// Round 5
// 211.163 us; speedup vs baseline: 4.6211x; 1.0723x over previous
//
#include <hip/hip_runtime.h>
#include <hip/hip_bf16.h>
#include <math.h>

#define SEQ   2048
#define NB    4
#define CDIM  512
#define NHEAD 8
#define HD    64
// scale * log2(e): folded into K channels at the qkv GEMM epilogue
#define SL    (0.125f * 1.4426950408889634f)

typedef __attribute__((ext_vector_type(8))) short short8;
typedef __attribute__((ext_vector_type(8))) _Float16 f16x8;
typedef __attribute__((ext_vector_type(4))) _Float16 f16x4;
typedef __attribute__((ext_vector_type(4))) float f32x4;

__device__ inline f32x4 mfmaH(f16x8 a, f16x8 b, f32x4 c) {
    return __builtin_amdgcn_mfma_f32_16x16x32_f16(a, b, c, 0, 0, 0);
}
__device__ inline f32x4 mfmaB(short8 a, short8 b, f32x4 c) {
    return __builtin_amdgcn_mfma_f32_16x16x32_bf16(a, b, c, 0, 0, 0);
}

__device__ inline ushort bf16_rne(float f) {
    union { float f; unsigned u; } c; c.f = f;
    unsigned u = c.u + 0x7fffu + ((c.u >> 16) & 1u);
    return (ushort)(u >> 16);
}
__device__ inline float bf16_to_f(ushort h) {
    union { unsigned u; float f; } c; c.u = ((unsigned)h) << 16;
    return c.f;
}

// Universal LDS tile layout: [rows][64 cols of 2B] = 128B pitch.
// XOR byte bits [6:4] with (row&7)^((row>>3)&7): conflict-free b128 frag
// reads (16 lanes @ 128B stride) and near-free staging writes.
__device__ inline int swz_off(int row, int byte_in_row) {
    return row * 128 + (byte_in_row ^ ((((row & 7) ^ ((row >> 3) & 7))) << 4));
}

__device__ inline f16x8 fragH(const _Float16* base, int row, int kbyte) {
    return *(const f16x8*)(base + (swz_off(row, kbyte) >> 1));
}
__device__ inline short8 fragB(const ushort* base, int row, int kbyte) {
    return *(const short8*)(base + (swz_off(row, kbyte) >> 1));
}

// linear stage: 64x64 2B tile; src row pitch = spitch elems.
__device__ inline void stage64(_Float16* dst, const _Float16* src, int spitch, int tid) {
    int row = tid >> 2, q = tid & 3;
    const _Float16* s = src + (size_t)row * spitch + q * 16;
    f16x8 a = *(const f16x8*)(s);
    f16x8 b = *(const f16x8*)(s + 8);
    *(f16x8*)(dst + (swz_off(row, q * 32) >> 1))      = a;
    *(f16x8*)(dst + (swz_off(row, q * 32 + 16) >> 1)) = b;
}

// linear stage: 128x64 2B tile; src row pitch = 512 elems (K dim).
__device__ inline void stage128(ushort* dst, const ushort* src, int tid) {
    const int row = tid >> 1, half = tid & 1;
    const ushort* s = src + (size_t)row * 512 + half * 32;
    #pragma unroll
    for (int c = 0; c < 4; ++c) {
        short8 v = *(const short8*)(s + c * 8);
        *(short8*)(dst + (swz_off(row, half * 64 + c * 16) >> 1)) = v;
    }
}

// ---------------------------------------------------------------------------
// conv_w: split both weight matrices into bf16 hi/lo.
// ---------------------------------------------------------------------------
__global__ __launch_bounds__(256)
void conv_w(const float* __restrict__ w1, const float* __restrict__ w2,
            ushort* __restrict__ w1h, ushort* __restrict__ w1l,
            ushort* __restrict__ w2h, ushort* __restrict__ w2l)
{
    const size_t NW1 = (size_t)3 * CDIM * CDIM;
    size_t i = ((size_t)blockIdx.x * 256 + threadIdx.x) * 8;
    const float* src; ushort *dh, *dl;
    if (i < NW1) { src = w1 + i; dh = w1h + i; dl = w1l + i; }
    else { size_t j = i - NW1; src = w2 + j; dh = w2h + j; dl = w2l + j; }
    float4 a = *(const float4*)src, b = *(const float4*)(src + 4);
    float f[8] = {a.x, a.y, a.z, a.w, b.x, b.y, b.z, b.w};
    short8 hv, lv;
    #pragma unroll
    for (int e = 0; e < 8; ++e) {
        ushort hi = bf16_rne(f[e]);
        hv[e] = (short)hi;
        lv[e] = (short)bf16_rne(f[e] - bf16_to_f(hi));
    }
    *(short8*)dh = hv; *(short8*)dl = lv;
}

// ---------------------------------------------------------------------------
// conv_x: x[b][c][n] f32 -> xT[b][n][c] split bf16 hi/lo (LDS-tiled transpose)
// ---------------------------------------------------------------------------
__global__ __launch_bounds__(256)
void conv_x(const float* __restrict__ x, ushort* __restrict__ xh, ushort* __restrict__ xl)
{
    __shared__ float T[64][65];
    const int n0 = blockIdx.x * 64, c0 = blockIdx.y * 64, b = blockIdx.z;
    const int t = threadIdx.x, r = t >> 2, q = t & 3;
    const float* src = x + ((size_t)b * CDIM + c0 + r) * SEQ + n0 + q * 16;
    #pragma unroll
    for (int c = 0; c < 4; ++c) {
        float4 v = *(const float4*)(src + c * 4);
        T[r][q * 16 + c * 4 + 0] = v.x; T[r][q * 16 + c * 4 + 1] = v.y;
        T[r][q * 16 + c * 4 + 2] = v.z; T[r][q * 16 + c * 4 + 3] = v.w;
    }
    __syncthreads();
    short8 hv[2], lv[2];
    #pragma unroll
    for (int k = 0; k < 16; ++k) {
        float f = T[q * 16 + k][r];
        ushort hi = bf16_rne(f);
        hv[k >> 3][k & 7] = (short)hi;
        lv[k >> 3][k & 7] = (short)bf16_rne(f - bf16_to_f(hi));
    }
    size_t o = ((size_t)b * SEQ + n0 + r) * CDIM + c0 + q * 16;
    *(short8*)(xh + o) = hv[0]; *(short8*)(xh + o + 8) = hv[1];
    *(short8*)(xl + o) = lv[0]; *(short8*)(xl + o + 8) = lv[1];
}

// ---------------------------------------------------------------------------
// Split-bf16 MFMA GEMM: D[m][n] = sum_k A[m][k]*B[n][k], K=512, bf16x3.
// Block 128m x 128n, BK=64, 4 waves (2x2), 64x64 per wave.
// EPI 0 (qkv): m=seq, n=ch -> qkT[seq][128] fp16 (K scaled SL), vT[seq][64] fp16
// EPI 1 (proj): m=co, n=seq -> out[b][co][n] f32 + bias
// ---------------------------------------------------------------------------
template<int EPI>
__global__ __launch_bounds__(256)
void gemm_sp(const ushort* __restrict__ AH, const ushort* __restrict__ AL, size_t sA,
             const ushort* __restrict__ BH, const ushort* __restrict__ BL, size_t sB,
             _Float16* __restrict__ qkT, _Float16* __restrict__ vT,
             float* __restrict__ outp, const float* __restrict__ bias)
{
    const int bn = blockIdx.x * 128, bm = blockIdx.y * 128, bat = blockIdx.z;
    __shared__ __align__(16) ushort sAH[8192], sAL[8192], sBH[8192], sBL[8192];
    const int tid = threadIdx.x;
    const int w = tid >> 6, lane = tid & 63, l15 = lane & 15, g = lane >> 4;
    const int wm = w >> 1, wn = w & 1;
    const ushort* Ah = AH + sA * bat + (size_t)bm * 512;
    const ushort* Al = AL + sA * bat + (size_t)bm * 512;
    const ushort* Bh = BH + sB * bat + (size_t)bn * 512;
    const ushort* Bl = BL + sB * bat + (size_t)bn * 512;

    f32x4 acc[4][4] = {};

    for (int k0 = 0; k0 < 512; k0 += 64) {
        __syncthreads();
        stage128(sAH, Ah + k0, tid);
        stage128(sAL, Al + k0, tid);
        stage128(sBH, Bh + k0, tid);
        stage128(sBL, Bl + k0, tid);
        __syncthreads();
        #pragma unroll
        for (int kh = 0; kh < 2; ++kh) {
            short8 bh[4], bl[4];
            #pragma unroll
            for (int nf = 0; nf < 4; ++nf) {
                bh[nf] = fragB(sBH, 64 * wn + 16 * nf + l15, kh * 64 + g * 16);
                bl[nf] = fragB(sBL, 64 * wn + 16 * nf + l15, kh * 64 + g * 16);
            }
            #pragma unroll
            for (int mf = 0; mf < 4; ++mf) {
                short8 ah = fragB(sAH, 64 * wm + 16 * mf + l15, kh * 64 + g * 16);
                short8 al = fragB(sAL, 64 * wm + 16 * mf + l15, kh * 64 + g * 16);
                #pragma unroll
                for (int nf = 0; nf < 4; ++nf) {
                    acc[mf][nf] = mfmaB(ah, bh[nf], acc[mf][nf]);
                    acc[mf][nf] = mfmaB(ah, bl[nf], acc[mf][nf]);
                    acc[mf][nf] = mfmaB(al, bh[nf], acc[mf][nf]);
                }
            }
        }
    }

    if (EPI == 0) {
        #pragma unroll
        for (int nf = 0; nf < 4; ++nf) {
            const int c0 = bn + 64 * wn + 16 * nf;   // frag-uniform (16 | boundaries)
            const int h = c0 / 192, rr = c0 % 192;
            if (rr < 128) {
                const float sc = (rr < 64) ? 1.0f : SL;
                _Float16* base = qkT + ((size_t)(bat * NHEAD + h) * SEQ) * 128 + rr + l15;
                #pragma unroll
                for (int mf = 0; mf < 4; ++mf)
                    #pragma unroll
                    for (int r = 0; r < 4; ++r) {
                        const int sj = bm + 64 * wm + 16 * mf + 4 * g + r;
                        base[(size_t)sj * 128] = (_Float16)(acc[mf][nf][r] * sc);
                    }
            } else {
                _Float16* base = vT + ((size_t)(bat * NHEAD + h) * SEQ) * HD + (rr - 128) + l15;
                #pragma unroll
                for (int mf = 0; mf < 4; ++mf)
                    #pragma unroll
                    for (int r = 0; r < 4; ++r) {
                        const int sj = bm + 64 * wm + 16 * mf + 4 * g + r;
                        base[(size_t)sj * HD] = (_Float16)acc[mf][nf][r];
                    }
            }
        }
    } else {
        #pragma unroll
        for (int mf = 0; mf < 4; ++mf)
            #pragma unroll
            for (int r = 0; r < 4; ++r) {
                const int co = bm + 64 * wm + 16 * mf + 4 * g + r;
                const float bv = bias[co];
                float* base = outp + ((size_t)bat * CDIM + co) * SEQ + bn + 64 * wn + l15;
                #pragma unroll
                for (int nf = 0; nf < 4; ++nf)
                    base[16 * nf] = acc[mf][nf][r] + bv;
            }
    }
}

// ---------------------------------------------------------------------------
// Pass 1: c_i = log2 sum_j 2^(S_ij), S = K'^T Q over d=64 (SL pre-folded in K).
// 128-j chunks per iter (halves barrier/stage count). K-frags hoisted.
// ---------------------------------------------------------------------------
__global__ __launch_bounds__(256)
void attn_pass1(const _Float16* __restrict__ qkT, float* __restrict__ cvals)
{
    const int it = blockIdx.x, bh = blockIdx.y;
    const _Float16* tb = qkT + ((size_t)bh * SEQ) * 128;
    const int i0 = it * 64;

    __shared__ __align__(16) _Float16 Kt[4096];
    __shared__ __align__(16) _Float16 Qt[8192];   // 128 j x 64 d
    __shared__ float red[4][64];

    const int tid = threadIdx.x;
    const int w = tid >> 6, lane = tid & 63, l15 = lane & 15, g = lane >> 4;
    const int jrow = 16 * w + l15;

    stage64(Kt, tb + (size_t)i0 * 128 + 64, 128, tid);   // K cols 64..127
    __syncthreads();

    f16x8 kf[4][2];
    #pragma unroll
    for (int mf = 0; mf < 4; ++mf) {
        kf[mf][0] = fragH(Kt, 16 * mf + l15, g * 16);
        kf[mf][1] = fragH(Kt, 16 * mf + l15, 64 + g * 16);
    }

    float lsum[4][4] = {};

    for (int jt = 0; jt < 16; ++jt) {
        __syncthreads();
        stage64(Qt,        tb + (size_t)(jt * 128) * 128, 128, tid);
        stage64(Qt + 4096, tb + (size_t)(jt * 128 + 64) * 128, 128, tid);
        __syncthreads();

        #pragma unroll
        for (int jh = 0; jh < 2; ++jh) {
            f16x8 qb0 = fragH(Qt, 64 * jh + jrow, g * 16);
            f16x8 qb1 = fragH(Qt, 64 * jh + jrow, 64 + g * 16);
            #pragma unroll
            for (int mf = 0; mf < 4; ++mf) {
                f32x4 s = {0.f, 0.f, 0.f, 0.f};
                s = mfmaH(kf[mf][0], qb0, s);
                s = mfmaH(kf[mf][1], qb1, s);
                #pragma unroll
                for (int r = 0; r < 4; ++r)
                    lsum[mf][r] += exp2f(s[r]);
            }
        }
    }

    #pragma unroll
    for (int mf = 0; mf < 4; ++mf)
        #pragma unroll
        for (int r = 0; r < 4; ++r) {
            float v = lsum[mf][r];
            v += __shfl_xor(v, 1); v += __shfl_xor(v, 2);
            v += __shfl_xor(v, 4); v += __shfl_xor(v, 8);
            lsum[mf][r] = v;
        }
    __syncthreads();
    if (l15 == 0) {
        #pragma unroll
        for (int mf = 0; mf < 4; ++mf)
            #pragma unroll
            for (int r = 0; r < 4; ++r)
                red[w][16 * mf + 4 * g + r] = lsum[mf][r];
    }
    __syncthreads();
    if (tid < 64) {
        float s = red[0][tid] + red[1][tid] + red[2][tid] + red[3][tid];
        cvals[(size_t)bh * SEQ + i0 + tid] = log2f(s);
    }
}

// ---------------------------------------------------------------------------
// prescale_v: vT[bh][i][d] f16 -> vf16[bh][d][i] f16, scaled by 2^(-c_i/2).
// ---------------------------------------------------------------------------
__global__ __launch_bounds__(256)
void prescale_v(const _Float16* __restrict__ vT, const float* __restrict__ cvals,
                _Float16* __restrict__ vf16)
{
    __shared__ float T[64][65];
    const int i0 = blockIdx.x * 64, bh = blockIdx.y;
    const int t = threadIdx.x, r = t >> 2, q = t & 3;
    const float cf = exp2f(-0.5f * cvals[(size_t)bh * SEQ + i0 + r]);
    const _Float16* src = vT + ((size_t)bh * SEQ + i0 + r) * HD + q * 16;
    f16x8 a = *(const f16x8*)src, b = *(const f16x8*)(src + 8);
    #pragma unroll
    for (int k = 0; k < 8; ++k) {
        T[r][q * 16 + k]     = (float)a[k] * cf;
        T[r][q * 16 + 8 + k] = (float)b[k] * cf;
    }
    __syncthreads();
    f16x8 o0, o1;
    #pragma unroll
    for (int k = 0; k < 8; ++k) {
        o0[k] = (_Float16)T[q * 16 + k][r];
        o1[k] = (_Float16)T[q * 16 + 8 + k][r];
    }
    _Float16* dst = vf16 + ((size_t)bh * HD + r) * SEQ + i0 + q * 16;
    *(f16x8*)dst = o0; *(f16x8*)(dst + 8) = o1;
}

// ---------------------------------------------------------------------------
// Pass 2 v2: outT[j][d] = sum_i P^T[j][i] * V''^T[i][d], P = 2^(S - c/2).
// 128-j tile, 4 waves. Wave w owns i-quadrant (QK^T A-operand) and d-quadrant
// (PV B-operand): K/V frag reads 2 each (no 4x duplication); Q-frags (8x2)
// hoisted in registers; c_i fetched as one broadcast float4 per lane (no
// bpermute). P goes through a 16KB LDS tile (aliases dead Q staging tile).
// ---------------------------------------------------------------------------
__global__ __launch_bounds__(256, 2)
void attn_pass2(const _Float16* __restrict__ qkT, const _Float16* __restrict__ vf16,
                const float* __restrict__ cvals,
                ushort* __restrict__ aoth, ushort* __restrict__ aotl)
{
    const int jt = blockIdx.x, bh = blockIdx.y;
    const int b = bh >> 3, h = bh & 7;
    const _Float16* tb = qkT + ((size_t)bh * SEQ) * 128;
    const _Float16* vb = vf16 + ((size_t)bh * HD) * SEQ;
    const float* cp = cvals + (size_t)bh * SEQ;
    const int j0 = jt * 128;

    __shared__ __align__(16) _Float16 Kt[4096];   // 64 i x 64 d
    __shared__ __align__(16) _Float16 Vt[4096];   // 64 d x 64 i
    __shared__ __align__(16) _Float16 Pt[8192];   // 128 j x 64 i (aliases Qt)
    _Float16* Qt = Pt;                            // 128 j x 64 d during init

    const int tid = threadIdx.x;
    const int w = tid >> 6, lane = tid & 63, l15 = lane & 15, g = lane >> 4;

    // stage Q 128x64 once, hoist all B-frags (8 jf x 2 kh)
    stage64(Qt,        tb + (size_t)j0 * 128, 128, tid);
    stage64(Qt + 4096, tb + (size_t)(j0 + 64) * 128, 128, tid);
    __syncthreads();
    f16x8 qf[8][2];
    #pragma unroll
    for (int jf = 0; jf < 8; ++jf) {
        qf[jf][0] = fragH(Qt, 16 * jf + l15, g * 16);
        qf[jf][1] = fragH(Qt, 16 * jf + l15, 64 + g * 16);
    }

    f32x4 oacc[8] = {};

    for (int ic = 0; ic < 32; ++ic) {
        const int i0 = ic * 64;
        __syncthreads();              // prev-iter Kt/Vt/Pt readers done (Qt hoist for ic=0)
        stage64(Kt, tb + (size_t)i0 * 128 + 64, 128, tid);
        stage64(Vt, vb + i0, SEQ, tid);
        const float4 cv4 = *(const float4*)(cp + i0 + 16 * w + 4 * g);
        __syncthreads();

        // QK^T: A = K rows (i-quadrant w), B = hoisted Q-frags
        f16x8 kf0 = fragH(Kt, 16 * w + l15, g * 16);
        f16x8 kf1 = fragH(Kt, 16 * w + l15, 64 + g * 16);
        const float c0h = 0.5f * cv4.x, c1h = 0.5f * cv4.y;
        const float c2h = 0.5f * cv4.z, c3h = 0.5f * cv4.w;
        #pragma unroll
        for (int jf = 0; jf < 8; ++jf) {
            f32x4 s = {0.f, 0.f, 0.f, 0.f};
            s = mfmaH(kf0, qf[jf][0], s);
            s = mfmaH(kf1, qf[jf][1], s);
            f16x4 pv;
            pv[0] = (_Float16)exp2f(s[0] - c0h);
            pv[1] = (_Float16)exp2f(s[1] - c1h);
            pv[2] = (_Float16)exp2f(s[2] - c2h);
            pv[3] = (_Float16)exp2f(s[3] - c3h);
            // P[i = i0+16w+4g+r][j = j0+16jf+l15] -> Pt[row=j][col=i]
            *(f16x4*)(Pt + (swz_off(16 * jf + l15, (16 * w + 4 * g) * 2) >> 1)) = pv;
        }
        __syncthreads();              // P visible to all waves

        // PV: A = P-frags (8 jf x 2 kh), B = V rows (d-quadrant w)
        f16x8 vf0 = fragH(Vt, 16 * w + l15, g * 16);
        f16x8 vf1 = fragH(Vt, 16 * w + l15, 64 + g * 16);
        #pragma unroll
        for (int jf = 0; jf < 8; ++jf) {
            f16x8 p0 = fragH(Pt, 16 * jf + l15, g * 16);
            f16x8 p1 = fragH(Pt, 16 * jf + l15, 64 + g * 16);
            oacc[jf] = mfmaH(p0, vf0, oacc[jf]);
            oacc[jf] = mfmaH(p1, vf1, oacc[jf]);
        }
    }

    // write aoutT[j][h*64 + d] split bf16; d = 16w + l15 (32B coalesced segs)
    #pragma unroll
    for (int jf = 0; jf < 8; ++jf)
        #pragma unroll
        for (int r = 0; r < 4; ++r) {
            const int j = j0 + 16 * jf + 4 * g + r;
            const int ch = h * HD + 16 * w + l15;
            const size_t idx = ((size_t)b * SEQ + j) * CDIM + ch;
            float v = oacc[jf][r];
            ushort hi = bf16_rne(v);
            aoth[idx] = hi;
            aotl[idx] = bf16_rne(v - bf16_to_f(hi));
        }
}

// ---------------------------------------------------------------------------
extern "C" void kernel_launch(void* const* d_in, const int* in_sizes, int n_in,
                              void* d_out, int out_size, void* d_ws, size_t ws_size,
                              hipStream_t stream)
{
    const float* x      = (const float*)d_in[0];   // [4][512][2048]
    const float* w_qkv  = (const float*)d_in[1];   // [1536][512]
    const float* w_proj = (const float*)d_in[2];   // [512][512]
    const float* b_proj = (const float*)d_in[3];   // [512]
    float* out = (float*)d_out;                    // [4][512][2048]

    char* p = (char*)d_ws;
    auto alloc = [&](size_t bytes) { char* q = p; p += (bytes + 255) & ~(size_t)255; return q; };
    _Float16* qkT  = (_Float16*)alloc((size_t)NB * NHEAD * SEQ * 128 * 2); // 16 MB
    _Float16* vT   = (_Float16*)alloc((size_t)NB * NHEAD * SEQ * HD * 2);  // 8 MB
    float*    cvals = (float*)alloc((size_t)NB * NHEAD * SEQ * 4);         // 256 KB
    ushort*   xTh  = (ushort*)alloc((size_t)NB * SEQ * CDIM * 2);          // 8 MB
    ushort*   xTl  = (ushort*)alloc((size_t)NB * SEQ * CDIM * 2);          // 8 MB
    ushort*   wqh  = (ushort*)alloc((size_t)3 * CDIM * CDIM * 2);
    ushort*   wql  = (ushort*)alloc((size_t)3 * CDIM * CDIM * 2);
    ushort*   wph  = (ushort*)alloc((size_t)CDIM * CDIM * 2);
    ushort*   wpl  = (ushort*)alloc((size_t)CDIM * CDIM * 2);
    ushort*   aoth = (ushort*)alloc((size_t)NB * SEQ * CDIM * 2);          // 8 MB
    ushort*   aotl = (ushort*)alloc((size_t)NB * SEQ * CDIM * 2);          // 8 MB
    // vf16 aliases xTh: xT is dead after the qkv GEMM; prescale_v writes it
    // before attn_pass2 reads it (stream-ordered, deterministic each replay).
    _Float16* vf16 = (_Float16*)xTh;

    dim3 blk(256);
    // weight + input splits
    conv_w<<<dim3(512), blk, 0, stream>>>(w_qkv, w_proj, wqh, wql, wph, wpl);
    conv_x<<<dim3(SEQ / 64, CDIM / 64, NB), blk, 0, stream>>>(x, xTh, xTl);
    // qkv: D[seq][ch] -> qkT fp16 (K*SL) + vT fp16
    gemm_sp<0><<<dim3(12, 16, NB), blk, 0, stream>>>(
        xTh, xTl, (size_t)SEQ * CDIM, wqh, wql, 0,
        qkT, vT, nullptr, nullptr);
    // softmax row constants (log2 domain)
    attn_pass1<<<dim3(SEQ / 64, NB * NHEAD), blk, 0, stream>>>(qkT, cvals);
    // V'' = v * 2^(-c/2), transposed to [d][i] fp16
    prescale_v<<<dim3(SEQ / 64, NB * NHEAD), blk, 0, stream>>>(vT, cvals, vf16);
    // attention -> aoutT split bf16
    attn_pass2<<<dim3(SEQ / 128, NB * NHEAD), blk, 0, stream>>>(
        qkT, vf16, cvals, aoth, aotl);
    // proj: D[co][seq] = w_proj @ aout + bias
    gemm_sp<1><<<dim3(16, 4, NB), blk, 0, stream>>>(
        wph, wpl, 0, aoth, aotl, (size_t)SEQ * CDIM,
        nullptr, nullptr, out, b_proj);
}

// Round 7
// 206.077 us; speedup vs baseline: 4.7351x; 1.0247x over previous
//
#include <hip/hip_runtime.h>
#include <hip/hip_bf16.h>
#include <math.h>

#define SEQ   2048
#define NB    4
#define CDIM  512
#define NHEAD 8
#define HD    64
// scale * log2(e): folded into K channels at the qkv GEMM epilogue
#define SL    (0.125f * 1.4426950408889634f)

typedef __attribute__((ext_vector_type(8))) short short8;
typedef __attribute__((ext_vector_type(8))) _Float16 f16x8;
typedef __attribute__((ext_vector_type(4))) _Float16 f16x4;
typedef __attribute__((ext_vector_type(4))) float f32x4;

__device__ inline f32x4 mfmaH(f16x8 a, f16x8 b, f32x4 c) {
    return __builtin_amdgcn_mfma_f32_16x16x32_f16(a, b, c, 0, 0, 0);
}
__device__ inline f32x4 mfmaB(short8 a, short8 b, f32x4 c) {
    return __builtin_amdgcn_mfma_f32_16x16x32_bf16(a, b, c, 0, 0, 0);
}

__device__ inline ushort bf16_rne(float f) {
    union { float f; unsigned u; } c; c.f = f;
    unsigned u = c.u + 0x7fffu + ((c.u >> 16) & 1u);
    return (ushort)(u >> 16);
}
__device__ inline float bf16_to_f(ushort h) {
    union { unsigned u; float f; } c; c.u = ((unsigned)h) << 16;
    return c.f;
}

// LDS tile layout: [rows][64 cols of 2B] = 128B pitch, XOR-swizzled.
__device__ inline int swz_off(int row, int byte_in_row) {
    return row * 128 + (byte_in_row ^ ((((row & 7) ^ ((row >> 3) & 7))) << 4));
}
__device__ inline f16x8 fragH(const _Float16* base, int row, int kbyte) {
    return *(const f16x8*)(base + (swz_off(row, kbyte) >> 1));
}
__device__ inline short8 fragB(const ushort* base, int row, int kbyte) {
    return *(const short8*)(base + (swz_off(row, kbyte) >> 1));
}

// linear stage: 128x64 2B tile; src row pitch = 512 elems (K dim).
__device__ inline void stage128(ushort* dst, const ushort* src, int tid) {
    const int row = tid >> 1, half = tid & 1;
    const ushort* s = src + (size_t)row * 512 + half * 32;
    #pragma unroll
    for (int c = 0; c < 4; ++c) {
        short8 v = *(const short8*)(s + c * 8);
        *(short8*)(dst + (swz_off(row, half * 64 + c * 16) >> 1)) = v;
    }
}

// ---------------------------------------------------------------------------
// conv_w: split both weight matrices into bf16 hi/lo.
// ---------------------------------------------------------------------------
__global__ __launch_bounds__(256)
void conv_w(const float* __restrict__ w1, const float* __restrict__ w2,
            ushort* __restrict__ w1h, ushort* __restrict__ w1l,
            ushort* __restrict__ w2h, ushort* __restrict__ w2l)
{
    const size_t NW1 = (size_t)3 * CDIM * CDIM;
    size_t i = ((size_t)blockIdx.x * 256 + threadIdx.x) * 8;
    const float* src; ushort *dh, *dl;
    if (i < NW1) { src = w1 + i; dh = w1h + i; dl = w1l + i; }
    else { size_t j = i - NW1; src = w2 + j; dh = w2h + j; dl = w2l + j; }
    float4 a = *(const float4*)src, b = *(const float4*)(src + 4);
    float f[8] = {a.x, a.y, a.z, a.w, b.x, b.y, b.z, b.w};
    short8 hv, lv;
    #pragma unroll
    for (int e = 0; e < 8; ++e) {
        ushort hi = bf16_rne(f[e]);
        hv[e] = (short)hi;
        lv[e] = (short)bf16_rne(f[e] - bf16_to_f(hi));
    }
    *(short8*)dh = hv; *(short8*)dl = lv;
}

// ---------------------------------------------------------------------------
// conv_x: x[b][c][n] f32 -> xT[b][n][c] split bf16 hi/lo (LDS-tiled transpose)
// ---------------------------------------------------------------------------
__global__ __launch_bounds__(256)
void conv_x(const float* __restrict__ x, ushort* __restrict__ xh, ushort* __restrict__ xl)
{
    __shared__ float T[64][65];
    const int n0 = blockIdx.x * 64, c0 = blockIdx.y * 64, b = blockIdx.z;
    const int t = threadIdx.x, r = t >> 2, q = t & 3;
    const float* src = x + ((size_t)b * CDIM + c0 + r) * SEQ + n0 + q * 16;
    #pragma unroll
    for (int c = 0; c < 4; ++c) {
        float4 v = *(const float4*)(src + c * 4);
        T[r][q * 16 + c * 4 + 0] = v.x; T[r][q * 16 + c * 4 + 1] = v.y;
        T[r][q * 16 + c * 4 + 2] = v.z; T[r][q * 16 + c * 4 + 3] = v.w;
    }
    __syncthreads();
    short8 hv[2], lv[2];
    #pragma unroll
    for (int k = 0; k < 16; ++k) {
        float f = T[q * 16 + k][r];
        ushort hi = bf16_rne(f);
        hv[k >> 3][k & 7] = (short)hi;
        lv[k >> 3][k & 7] = (short)bf16_rne(f - bf16_to_f(hi));
    }
    size_t o = ((size_t)b * SEQ + n0 + r) * CDIM + c0 + q * 16;
    *(short8*)(xh + o) = hv[0]; *(short8*)(xh + o + 8) = hv[1];
    *(short8*)(xl + o) = lv[0]; *(short8*)(xl + o + 8) = lv[1];
}

// ---------------------------------------------------------------------------
// Split-bf16 MFMA GEMM: D[m][n] = sum_k A[m][k]*B[n][k], K=512, bf16x3.
// Block 128m x 128n, BK=64, 4 waves (2x2), 64x64 per wave.
// EPI 0 (qkv): m=seq, n=ch -> qkT[seq][128] fp16 (K scaled SL), vT[seq][64] fp16
// EPI 1 (proj): m=co, n=seq -> out[b][co][n] f32 + bias
// ---------------------------------------------------------------------------
template<int EPI>
__global__ __launch_bounds__(256)
void gemm_sp(const ushort* __restrict__ AH, const ushort* __restrict__ AL, size_t sA,
             const ushort* __restrict__ BH, const ushort* __restrict__ BL, size_t sB,
             _Float16* __restrict__ qkT, _Float16* __restrict__ vT,
             float* __restrict__ outp, const float* __restrict__ bias)
{
    const int bn = blockIdx.x * 128, bm = blockIdx.y * 128, bat = blockIdx.z;
    __shared__ __align__(16) ushort sAH[8192], sAL[8192], sBH[8192], sBL[8192];
    const int tid = threadIdx.x;
    const int w = tid >> 6, lane = tid & 63, l15 = lane & 15, g = lane >> 4;
    const int wm = w >> 1, wn = w & 1;
    const ushort* Ah = AH + sA * bat + (size_t)bm * 512;
    const ushort* Al = AL + sA * bat + (size_t)bm * 512;
    const ushort* Bh = BH + sB * bat + (size_t)bn * 512;
    const ushort* Bl = BL + sB * bat + (size_t)bn * 512;

    f32x4 acc[4][4] = {};

    for (int k0 = 0; k0 < 512; k0 += 64) {
        __syncthreads();
        stage128(sAH, Ah + k0, tid);
        stage128(sAL, Al + k0, tid);
        stage128(sBH, Bh + k0, tid);
        stage128(sBL, Bl + k0, tid);
        __syncthreads();
        #pragma unroll
        for (int kh = 0; kh < 2; ++kh) {
            short8 bh[4], bl[4];
            #pragma unroll
            for (int nf = 0; nf < 4; ++nf) {
                bh[nf] = fragB(sBH, 64 * wn + 16 * nf + l15, kh * 64 + g * 16);
                bl[nf] = fragB(sBL, 64 * wn + 16 * nf + l15, kh * 64 + g * 16);
            }
            #pragma unroll
            for (int mf = 0; mf < 4; ++mf) {
                short8 ah = fragB(sAH, 64 * wm + 16 * mf + l15, kh * 64 + g * 16);
                short8 al = fragB(sAL, 64 * wm + 16 * mf + l15, kh * 64 + g * 16);
                #pragma unroll
                for (int nf = 0; nf < 4; ++nf) {
                    acc[mf][nf] = mfmaB(ah, bh[nf], acc[mf][nf]);
                    acc[mf][nf] = mfmaB(ah, bl[nf], acc[mf][nf]);
                    acc[mf][nf] = mfmaB(al, bh[nf], acc[mf][nf]);
                }
            }
        }
    }

    if (EPI == 0) {
        #pragma unroll
        for (int nf = 0; nf < 4; ++nf) {
            const int c0 = bn + 64 * wn + 16 * nf;   // frag-uniform (16 | boundaries)
            const int h = c0 / 192, rr = c0 % 192;
            if (rr < 128) {
                const float sc = (rr < 64) ? 1.0f : SL;
                _Float16* base = qkT + ((size_t)(bat * NHEAD + h) * SEQ) * 128 + rr + l15;
                #pragma unroll
                for (int mf = 0; mf < 4; ++mf)
                    #pragma unroll
                    for (int r = 0; r < 4; ++r) {
                        const int sj = bm + 64 * wm + 16 * mf + 4 * g + r;
                        base[(size_t)sj * 128] = (_Float16)(acc[mf][nf][r] * sc);
                    }
            } else {
                _Float16* base = vT + ((size_t)(bat * NHEAD + h) * SEQ) * HD + (rr - 128) + l15;
                #pragma unroll
                for (int mf = 0; mf < 4; ++mf)
                    #pragma unroll
                    for (int r = 0; r < 4; ++r) {
                        const int sj = bm + 64 * wm + 16 * mf + 4 * g + r;
                        base[(size_t)sj * HD] = (_Float16)acc[mf][nf][r];
                    }
            }
        }
    } else {
        #pragma unroll
        for (int mf = 0; mf < 4; ++mf)
            #pragma unroll
            for (int r = 0; r < 4; ++r) {
                const int co = bm + 64 * wm + 16 * mf + 4 * g + r;
                const float bv = bias[co];
                float* base = outp + ((size_t)bat * CDIM + co) * SEQ + bn + 64 * wn + l15;
                #pragma unroll
                for (int nf = 0; nf < 4; ++nf)
                    base[16 * nf] = acc[mf][nf][r] + bv;
            }
    }
}

// ---------------------------------------------------------------------------
// Pass 1 v3: c_i = log2 sum_j 2^(S_ij). All operands read DIRECTLY from
// global (L1/L2-resident): no LDS, no barriers in the loop. K-frags hoisted.
// Block: 64-i tile; waves split j (16 each per 64-chunk).
// ---------------------------------------------------------------------------
__global__ __launch_bounds__(256, 4)
void attn_pass1(const _Float16* __restrict__ qkT, float* __restrict__ cvals)
{
    const int it = blockIdx.x, bh = blockIdx.y;
    const _Float16* tb = qkT + ((size_t)bh * SEQ) * 128;
    const int i0 = it * 64;

    __shared__ float red[4][64];

    const int tid = threadIdx.x;
    const int w = tid >> 6, lane = tid & 63, l15 = lane & 15, g = lane >> 4;

    // hoist K A-frags: rows i = i0+16mf+l15, d = kh*32 + g*8 (+64 col offset)
    f16x8 kf[4][2];
    #pragma unroll
    for (int mf = 0; mf < 4; ++mf) {
        const _Float16* kb = tb + (size_t)(i0 + 16 * mf + l15) * 128 + 64 + g * 8;
        kf[mf][0] = *(const f16x8*)(kb);
        kf[mf][1] = *(const f16x8*)(kb + 32);
    }

    float lsum[4][4] = {};

    for (int jt = 0; jt < 32; ++jt) {
        const _Float16* qb = tb + (size_t)(jt * 64 + 16 * w + l15) * 128 + g * 8;
        f16x8 qb0 = *(const f16x8*)(qb);
        f16x8 qb1 = *(const f16x8*)(qb + 32);
        #pragma unroll
        for (int mf = 0; mf < 4; ++mf) {
            f32x4 s = {0.f, 0.f, 0.f, 0.f};
            s = mfmaH(kf[mf][0], qb0, s);
            s = mfmaH(kf[mf][1], qb1, s);
            #pragma unroll
            for (int r = 0; r < 4; ++r)
                lsum[mf][r] += exp2f(s[r]);
        }
    }

    #pragma unroll
    for (int mf = 0; mf < 4; ++mf)
        #pragma unroll
        for (int r = 0; r < 4; ++r) {
            float v = lsum[mf][r];
            v += __shfl_xor(v, 1); v += __shfl_xor(v, 2);
            v += __shfl_xor(v, 4); v += __shfl_xor(v, 8);
            lsum[mf][r] = v;
        }
    __syncthreads();
    if (l15 == 0) {
        #pragma unroll
        for (int mf = 0; mf < 4; ++mf)
            #pragma unroll
            for (int r = 0; r < 4; ++r)
                red[w][16 * mf + 4 * g + r] = lsum[mf][r];
    }
    __syncthreads();
    if (tid < 64) {
        float s = red[0][tid] + red[1][tid] + red[2][tid] + red[3][tid];
        cvals[(size_t)bh * SEQ + i0 + tid] = log2f(s);
    }
}

// ---------------------------------------------------------------------------
// prescale_v: vT[bh][i][d] f16 -> vf16[bh][d][i] f16, scaled by 2^(-c_i/2).
// ---------------------------------------------------------------------------
__global__ __launch_bounds__(256)
void prescale_v(const _Float16* __restrict__ vT, const float* __restrict__ cvals,
                _Float16* __restrict__ vf16)
{
    __shared__ float T[64][65];
    const int i0 = blockIdx.x * 64, bh = blockIdx.y;
    const int t = threadIdx.x, r = t >> 2, q = t & 3;
    const float cf = exp2f(-0.5f * cvals[(size_t)bh * SEQ + i0 + r]);
    const _Float16* src = vT + ((size_t)bh * SEQ + i0 + r) * HD + q * 16;
    f16x8 a = *(const f16x8*)src, b = *(const f16x8*)(src + 8);
    #pragma unroll
    for (int k = 0; k < 8; ++k) {
        T[r][q * 16 + k]     = (float)a[k] * cf;
        T[r][q * 16 + 8 + k] = (float)b[k] * cf;
    }
    __syncthreads();
    f16x8 o0, o1;
    #pragma unroll
    for (int k = 0; k < 8; ++k) {
        o0[k] = (_Float16)T[q * 16 + k][r];
        o1[k] = (_Float16)T[q * 16 + 8 + k][r];
    }
    _Float16* dst = vf16 + ((size_t)bh * HD + r) * SEQ + i0 + q * 16;
    *(f16x8*)dst = o0; *(f16x8*)(dst + 8) = o1;
}

// ---------------------------------------------------------------------------
// Pass 2 v3: outT[j][d] = sum_i P^T[j][i] * V''^T[i][d], P = 2^(S - c/2).
// 64-j tile (grid 1024 = 4 blocks/CU). K/V/Q frags read DIRECTLY from global;
// LDS holds only the double-buffered P transpose -> ONE barrier per iter.
// -c/2 folded into MFMA accumulator init; cvt_pkrtz packs P.
// Wave w: QK^T i-quadrant (rows 16w..16w+15), PV d-quadrant (cols 16w..16w+15).
// ---------------------------------------------------------------------------
__global__ __launch_bounds__(256, 4)
void attn_pass2(const _Float16* __restrict__ qkT, const _Float16* __restrict__ vf16,
                const float* __restrict__ cvals,
                ushort* __restrict__ aoth, ushort* __restrict__ aotl)
{
    const int jt = blockIdx.x, bh = blockIdx.y;
    const int b = bh >> 3, h = bh & 7;
    const _Float16* tb = qkT + ((size_t)bh * SEQ) * 128;
    const _Float16* vb = vf16 + ((size_t)bh * HD) * SEQ;
    const float* cp = cvals + (size_t)bh * SEQ;
    const int j0 = jt * 64;

    __shared__ __align__(16) _Float16 Pt[2][4096];   // [buf][64 j][64 i] swizzled

    const int tid = threadIdx.x;
    const int w = tid >> 6, lane = tid & 63, l15 = lane & 15, g = lane >> 4;

    // hoist Q B-frags: rows j = j0+16jf+l15, d = kh*32 + g*8
    f16x8 qf[4][2];
    #pragma unroll
    for (int jf = 0; jf < 4; ++jf) {
        const _Float16* qb = tb + (size_t)(j0 + 16 * jf + l15) * 128 + g * 8;
        qf[jf][0] = *(const f16x8*)(qb);
        qf[jf][1] = *(const f16x8*)(qb + 32);
    }

    f32x4 oacc[4] = {};

    for (int ic = 0; ic < 32; ++ic) {
        const int i0 = ic * 64;
        // direct global frag loads (issued early; L1/L2-resident)
        const _Float16* kb = tb + (size_t)(i0 + 16 * w + l15) * 128 + 64 + g * 8;
        f16x8 kf0 = *(const f16x8*)(kb);
        f16x8 kf1 = *(const f16x8*)(kb + 32);
        const _Float16* vbp = vb + (size_t)(16 * w + l15) * SEQ + i0 + g * 8;
        f16x8 vf0 = *(const f16x8*)(vbp);
        f16x8 vf1 = *(const f16x8*)(vbp + 32);
        const float4 cv4 = *(const float4*)(cp + i0 + 16 * w + 4 * g);

        _Float16* Pw = &Pt[ic & 1][0];

        // QK^T: A = K (i-quadrant w), B = hoisted Q-frags; acc init = -c/2
        const f32x4 cinit = {-0.5f * cv4.x, -0.5f * cv4.y, -0.5f * cv4.z, -0.5f * cv4.w};
        #pragma unroll
        for (int jf = 0; jf < 4; ++jf) {
            f32x4 s = cinit;
            s = mfmaH(kf0, qf[jf][0], s);
            s = mfmaH(kf1, qf[jf][1], s);
            auto lo = __builtin_amdgcn_cvt_pkrtz(exp2f(s[0]), exp2f(s[1]));
            auto hi = __builtin_amdgcn_cvt_pkrtz(exp2f(s[2]), exp2f(s[3]));
            f16x4 pv;
            pv[0] = (_Float16)lo[0]; pv[1] = (_Float16)lo[1];
            pv[2] = (_Float16)hi[0]; pv[3] = (_Float16)hi[1];
            // P[i=i0+16w+4g+r][j=j0+16jf+l15] -> Pw[row=j][col-bytes (16w+4g)*2]
            *(f16x4*)(Pw + (swz_off(16 * jf + l15, 32 * w + 8 * g) >> 1)) = pv;
        }
        __syncthreads();              // P visible; prev buffer reads done implicitly

        // PV: A = P-frags (all 4 jf), B = V (d-quadrant w, direct global)
        #pragma unroll
        for (int jf = 0; jf < 4; ++jf) {
            f16x8 p0 = fragH(Pw, 16 * jf + l15, g * 16);
            f16x8 p1 = fragH(Pw, 16 * jf + l15, 64 + g * 16);
            oacc[jf] = mfmaH(p0, vf0, oacc[jf]);
            oacc[jf] = mfmaH(p1, vf1, oacc[jf]);
        }
    }

    // write aoutT[j][h*64 + d] split bf16; d = 16w + l15 (32B coalesced segs)
    #pragma unroll
    for (int jf = 0; jf < 4; ++jf)
        #pragma unroll
        for (int r = 0; r < 4; ++r) {
            const int j = j0 + 16 * jf + 4 * g + r;
            const int ch = h * HD + 16 * w + l15;
            const size_t idx = ((size_t)b * SEQ + j) * CDIM + ch;
            float v = oacc[jf][r];
            ushort hi = bf16_rne(v);
            aoth[idx] = hi;
            aotl[idx] = bf16_rne(v - bf16_to_f(hi));
        }
}

// ---------------------------------------------------------------------------
extern "C" void kernel_launch(void* const* d_in, const int* in_sizes, int n_in,
                              void* d_out, int out_size, void* d_ws, size_t ws_size,
                              hipStream_t stream)
{
    const float* x      = (const float*)d_in[0];   // [4][512][2048]
    const float* w_qkv  = (const float*)d_in[1];   // [1536][512]
    const float* w_proj = (const float*)d_in[2];   // [512][512]
    const float* b_proj = (const float*)d_in[3];   // [512]
    float* out = (float*)d_out;                    // [4][512][2048]

    char* p = (char*)d_ws;
    auto alloc = [&](size_t bytes) { char* q = p; p += (bytes + 255) & ~(size_t)255; return q; };
    _Float16* qkT  = (_Float16*)alloc((size_t)NB * NHEAD * SEQ * 128 * 2); // 16 MB
    _Float16* vT   = (_Float16*)alloc((size_t)NB * NHEAD * SEQ * HD * 2);  // 8 MB
    float*    cvals = (float*)alloc((size_t)NB * NHEAD * SEQ * 4);         // 256 KB
    ushort*   xTh  = (ushort*)alloc((size_t)NB * SEQ * CDIM * 2);          // 8 MB
    ushort*   xTl  = (ushort*)alloc((size_t)NB * SEQ * CDIM * 2);          // 8 MB
    ushort*   wqh  = (ushort*)alloc((size_t)3 * CDIM * CDIM * 2);
    ushort*   wql  = (ushort*)alloc((size_t)3 * CDIM * CDIM * 2);
    ushort*   wph  = (ushort*)alloc((size_t)CDIM * CDIM * 2);
    ushort*   wpl  = (ushort*)alloc((size_t)CDIM * CDIM * 2);
    ushort*   aoth = (ushort*)alloc((size_t)NB * SEQ * CDIM * 2);          // 8 MB
    ushort*   aotl = (ushort*)alloc((size_t)NB * SEQ * CDIM * 2);          // 8 MB
    // vf16 aliases xTh: xT is dead after the qkv GEMM; prescale_v writes it
    // before attn_pass2 reads it (stream-ordered, deterministic each replay).
    _Float16* vf16 = (_Float16*)xTh;

    dim3 blk(256);
    // weight + input splits
    conv_w<<<dim3(512), blk, 0, stream>>>(w_qkv, w_proj, wqh, wql, wph, wpl);
    conv_x<<<dim3(SEQ / 64, CDIM / 64, NB), blk, 0, stream>>>(x, xTh, xTl);
    // qkv: D[seq][ch] -> qkT fp16 (K*SL) + vT fp16
    gemm_sp<0><<<dim3(12, 16, NB), blk, 0, stream>>>(
        xTh, xTl, (size_t)SEQ * CDIM, wqh, wql, 0,
        qkT, vT, nullptr, nullptr);
    // softmax row constants (log2 domain)
    attn_pass1<<<dim3(SEQ / 64, NB * NHEAD), blk, 0, stream>>>(qkT, cvals);
    // V'' = v * 2^(-c/2), transposed to [d][i] fp16
    prescale_v<<<dim3(SEQ / 64, NB * NHEAD), blk, 0, stream>>>(vT, cvals, vf16);
    // attention -> aoutT split bf16
    attn_pass2<<<dim3(SEQ / 64, NB * NHEAD), blk, 0, stream>>>(
        qkT, vf16, cvals, aoth, aotl);
    // proj: D[co][seq] = w_proj @ aout + bias
    gemm_sp<1><<<dim3(16, 4, NB), blk, 0, stream>>>(
        wph, wpl, 0, aoth, aotl, (size_t)SEQ * CDIM,
        nullptr, nullptr, out, b_proj);
}

// Round 8
// 194.090 us; speedup vs baseline: 5.0276x; 1.0618x over previous
//
#include <hip/hip_runtime.h>
#include <hip/hip_bf16.h>
#include <math.h>

#define SEQ   2048
#define NB    4
#define CDIM  512
#define NHEAD 8
#define HD    64
// scale * log2(e): folded into K channels at the qkv GEMM epilogue
#define SL    (0.125f * 1.4426950408889634f)

typedef __attribute__((ext_vector_type(8))) short short8;
typedef __attribute__((ext_vector_type(8))) _Float16 f16x8;
typedef __attribute__((ext_vector_type(4))) _Float16 f16x4;
typedef __attribute__((ext_vector_type(4))) float f32x4;

__device__ inline f32x4 mfmaH(f16x8 a, f16x8 b, f32x4 c) {
    return __builtin_amdgcn_mfma_f32_16x16x32_f16(a, b, c, 0, 0, 0);
}
__device__ inline f32x4 mfmaB(short8 a, short8 b, f32x4 c) {
    return __builtin_amdgcn_mfma_f32_16x16x32_bf16(a, b, c, 0, 0, 0);
}

__device__ inline ushort bf16_rne(float f) {
    union { float f; unsigned u; } c; c.f = f;
    unsigned u = c.u + 0x7fffu + ((c.u >> 16) & 1u);
    return (ushort)(u >> 16);
}
__device__ inline float bf16_to_f(ushort h) {
    union { unsigned u; float f; } c; c.u = ((unsigned)h) << 16;
    return c.f;
}

// LDS tile layout: [rows][64 cols of 2B] = 128B pitch, XOR-swizzled.
__device__ inline int swz_off(int row, int byte_in_row) {
    return row * 128 + (byte_in_row ^ ((((row & 7) ^ ((row >> 3) & 7))) << 4));
}
__device__ inline f16x8 fragH(const _Float16* base, int row, int kbyte) {
    return *(const f16x8*)(base + (swz_off(row, kbyte) >> 1));
}
__device__ inline short8 fragB(const ushort* base, int row, int kbyte) {
    return *(const short8*)(base + (swz_off(row, kbyte) >> 1));
}

// linear stage: 128x64 2B tile; src row pitch = 512 elems (K dim).
__device__ inline void stage128(ushort* dst, const ushort* src, int tid) {
    const int row = tid >> 1, half = tid & 1;
    const ushort* s = src + (size_t)row * 512 + half * 32;
    #pragma unroll
    for (int c = 0; c < 4; ++c) {
        short8 v = *(const short8*)(s + c * 8);
        *(short8*)(dst + (swz_off(row, half * 64 + c * 16) >> 1)) = v;
    }
}

// ---------------------------------------------------------------------------
// conv_w: split both weight matrices into bf16 hi/lo.
// ---------------------------------------------------------------------------
__global__ __launch_bounds__(256)
void conv_w(const float* __restrict__ w1, const float* __restrict__ w2,
            ushort* __restrict__ w1h, ushort* __restrict__ w1l,
            ushort* __restrict__ w2h, ushort* __restrict__ w2l)
{
    const size_t NW1 = (size_t)3 * CDIM * CDIM;
    size_t i = ((size_t)blockIdx.x * 256 + threadIdx.x) * 8;
    const float* src; ushort *dh, *dl;
    if (i < NW1) { src = w1 + i; dh = w1h + i; dl = w1l + i; }
    else { size_t j = i - NW1; src = w2 + j; dh = w2h + j; dl = w2l + j; }
    float4 a = *(const float4*)src, b = *(const float4*)(src + 4);
    float f[8] = {a.x, a.y, a.z, a.w, b.x, b.y, b.z, b.w};
    short8 hv, lv;
    #pragma unroll
    for (int e = 0; e < 8; ++e) {
        ushort hi = bf16_rne(f[e]);
        hv[e] = (short)hi;
        lv[e] = (short)bf16_rne(f[e] - bf16_to_f(hi));
    }
    *(short8*)dh = hv; *(short8*)dl = lv;
}

// ---------------------------------------------------------------------------
// conv_x: x[b][c][n] f32 -> xT[b][n][c] plain bf16 (LDS-tiled transpose)
// ---------------------------------------------------------------------------
__global__ __launch_bounds__(256)
void conv_x(const float* __restrict__ x, ushort* __restrict__ xh)
{
    __shared__ float T[64][65];
    const int n0 = blockIdx.x * 64, c0 = blockIdx.y * 64, b = blockIdx.z;
    const int t = threadIdx.x, r = t >> 2, q = t & 3;
    const float* src = x + ((size_t)b * CDIM + c0 + r) * SEQ + n0 + q * 16;
    #pragma unroll
    for (int c = 0; c < 4; ++c) {
        float4 v = *(const float4*)(src + c * 4);
        T[r][q * 16 + c * 4 + 0] = v.x; T[r][q * 16 + c * 4 + 1] = v.y;
        T[r][q * 16 + c * 4 + 2] = v.z; T[r][q * 16 + c * 4 + 3] = v.w;
    }
    __syncthreads();
    short8 hv[2];
    #pragma unroll
    for (int k = 0; k < 16; ++k)
        hv[k >> 3][k & 7] = (short)bf16_rne(T[q * 16 + k][r]);
    size_t o = ((size_t)b * SEQ + n0 + r) * CDIM + c0 + q * 16;
    *(short8*)(xh + o) = hv[0]; *(short8*)(xh + o + 8) = hv[1];
}

// ---------------------------------------------------------------------------
// Split-bf16 MFMA GEMM: D[m][n] = sum_k A[m][k]*B[n][k], K=512.
// Block 128m x 128n, BK=64, 4 waves (2x2), 64x64 per wave.
// MODE 0 (qkv): A = xT plain bf16, B = w split (2 MFMA terms: A*Bh + A*Bl);
//               m=seq, n=ch -> qkT[seq][128] fp16 (K scaled SL), vT fp16.
// MODE 1 (proj): A = w split, B = aot split (3 terms); m=co, n=seq -> out+bias
// ---------------------------------------------------------------------------
template<int MODE>
__global__ __launch_bounds__(256)
void gemm_sp(const ushort* __restrict__ A0, const ushort* __restrict__ A1, size_t sA,
             const ushort* __restrict__ B0, const ushort* __restrict__ B1, size_t sB,
             _Float16* __restrict__ qkT, _Float16* __restrict__ vT,
             float* __restrict__ outp, const float* __restrict__ bias)
{
    const int bn = blockIdx.x * 128, bm = blockIdx.y * 128, bat = blockIdx.z;
    __shared__ __align__(16) ushort sA0[8192], sA1[8192], sB0[8192], sB1[8192];
    const int tid = threadIdx.x;
    const int w = tid >> 6, lane = tid & 63, l15 = lane & 15, g = lane >> 4;
    const int wm = w >> 1, wn = w & 1;
    const ushort* Ah = A0 + sA * bat + (size_t)bm * 512;
    const ushort* Al = (MODE == 1) ? A1 + sA * bat + (size_t)bm * 512 : nullptr;
    const ushort* Bh = B0 + sB * bat + (size_t)bn * 512;
    const ushort* Bl = B1 + sB * bat + (size_t)bn * 512;

    f32x4 acc[4][4] = {};

    for (int k0 = 0; k0 < 512; k0 += 64) {
        __syncthreads();
        stage128(sA0, Ah + k0, tid);
        if (MODE == 1) stage128(sA1, Al + k0, tid);
        stage128(sB0, Bh + k0, tid);
        stage128(sB1, Bl + k0, tid);
        __syncthreads();
        #pragma unroll
        for (int kh = 0; kh < 2; ++kh) {
            short8 bh[4], bl[4];
            #pragma unroll
            for (int nf = 0; nf < 4; ++nf) {
                bh[nf] = fragB(sB0, 64 * wn + 16 * nf + l15, kh * 64 + g * 16);
                bl[nf] = fragB(sB1, 64 * wn + 16 * nf + l15, kh * 64 + g * 16);
            }
            #pragma unroll
            for (int mf = 0; mf < 4; ++mf) {
                short8 ah = fragB(sA0, 64 * wm + 16 * mf + l15, kh * 64 + g * 16);
                #pragma unroll
                for (int nf = 0; nf < 4; ++nf) {
                    acc[mf][nf] = mfmaB(ah, bh[nf], acc[mf][nf]);
                    acc[mf][nf] = mfmaB(ah, bl[nf], acc[mf][nf]);
                }
                if (MODE == 1) {
                    short8 al = fragB(sA1, 64 * wm + 16 * mf + l15, kh * 64 + g * 16);
                    #pragma unroll
                    for (int nf = 0; nf < 4; ++nf)
                        acc[mf][nf] = mfmaB(al, bh[nf], acc[mf][nf]);
                }
            }
        }
    }

    if (MODE == 0) {
        #pragma unroll
        for (int nf = 0; nf < 4; ++nf) {
            const int c0 = bn + 64 * wn + 16 * nf;   // frag-uniform (16 | boundaries)
            const int h = c0 / 192, rr = c0 % 192;
            if (rr < 128) {
                const float sc = (rr < 64) ? 1.0f : SL;
                _Float16* base = qkT + ((size_t)(bat * NHEAD + h) * SEQ) * 128 + rr + l15;
                #pragma unroll
                for (int mf = 0; mf < 4; ++mf)
                    #pragma unroll
                    for (int r = 0; r < 4; ++r) {
                        const int sj = bm + 64 * wm + 16 * mf + 4 * g + r;
                        base[(size_t)sj * 128] = (_Float16)(acc[mf][nf][r] * sc);
                    }
            } else {
                _Float16* base = vT + ((size_t)(bat * NHEAD + h) * SEQ) * HD + (rr - 128) + l15;
                #pragma unroll
                for (int mf = 0; mf < 4; ++mf)
                    #pragma unroll
                    for (int r = 0; r < 4; ++r) {
                        const int sj = bm + 64 * wm + 16 * mf + 4 * g + r;
                        base[(size_t)sj * HD] = (_Float16)acc[mf][nf][r];
                    }
            }
        }
    } else {
        #pragma unroll
        for (int mf = 0; mf < 4; ++mf)
            #pragma unroll
            for (int r = 0; r < 4; ++r) {
                const int co = bm + 64 * wm + 16 * mf + 4 * g + r;
                const float bv = bias[co];
                float* base = outp + ((size_t)bat * CDIM + co) * SEQ + bn + 64 * wn + l15;
                #pragma unroll
                for (int nf = 0; nf < 4; ++nf)
                    base[16 * nf] = acc[mf][nf][r] + bv;
            }
    }
}

// ---------------------------------------------------------------------------
// Pass 1 v4: cvals_i = 0.5 * log2 sum_j 2^(S_ij). Direct-global operands,
// K-frags hoisted, Q software-prefetched one chunk ahead (2x unroll).
// ---------------------------------------------------------------------------
__global__ __launch_bounds__(256, 4)
void attn_pass1(const _Float16* __restrict__ qkT, float* __restrict__ cvals)
{
    const int it = blockIdx.x, bh = blockIdx.y;
    const _Float16* tb = qkT + ((size_t)bh * SEQ) * 128;
    const int i0 = it * 64;

    __shared__ float red[4][64];

    const int tid = threadIdx.x;
    const int w = tid >> 6, lane = tid & 63, l15 = lane & 15, g = lane >> 4;

    // hoist K A-frags: rows i = i0+16mf+l15, d = kh*32 + g*8 (+64 col offset)
    f16x8 kf[4][2];
    #pragma unroll
    for (int mf = 0; mf < 4; ++mf) {
        const _Float16* kb = tb + (size_t)(i0 + 16 * mf + l15) * 128 + 64 + g * 8;
        kf[mf][0] = *(const f16x8*)(kb);
        kf[mf][1] = *(const f16x8*)(kb + 32);
    }

    float lsum[4][4] = {};
    const _Float16* qrow = tb + (size_t)(16 * w + l15) * 128 + g * 8;

    f16x8 qa0 = *(const f16x8*)(qrow);
    f16x8 qa1 = *(const f16x8*)(qrow + 32);

    for (int jt = 0; jt < 32; jt += 2) {
        // prefetch jt+1
        const _Float16* qn = qrow + (size_t)(jt + 1) * 64 * 128;
        f16x8 qb0 = *(const f16x8*)(qn);
        f16x8 qb1 = *(const f16x8*)(qn + 32);
        #pragma unroll
        for (int mf = 0; mf < 4; ++mf) {
            f32x4 s = {0.f, 0.f, 0.f, 0.f};
            s = mfmaH(kf[mf][0], qa0, s);
            s = mfmaH(kf[mf][1], qa1, s);
            #pragma unroll
            for (int r = 0; r < 4; ++r) lsum[mf][r] += exp2f(s[r]);
        }
        // prefetch jt+2 (over-read at jt=30 lands in ws, never consumed wrongly)
        const _Float16* qn2 = qrow + (size_t)(jt + 2) * 64 * 128;
        qa0 = *(const f16x8*)(qn2);
        qa1 = *(const f16x8*)(qn2 + 32);
        #pragma unroll
        for (int mf = 0; mf < 4; ++mf) {
            f32x4 s = {0.f, 0.f, 0.f, 0.f};
            s = mfmaH(kf[mf][0], qb0, s);
            s = mfmaH(kf[mf][1], qb1, s);
            #pragma unroll
            for (int r = 0; r < 4; ++r) lsum[mf][r] += exp2f(s[r]);
        }
    }

    #pragma unroll
    for (int mf = 0; mf < 4; ++mf)
        #pragma unroll
        for (int r = 0; r < 4; ++r) {
            float v = lsum[mf][r];
            v += __shfl_xor(v, 1); v += __shfl_xor(v, 2);
            v += __shfl_xor(v, 4); v += __shfl_xor(v, 8);
            lsum[mf][r] = v;
        }
    __syncthreads();
    if (l15 == 0) {
        #pragma unroll
        for (int mf = 0; mf < 4; ++mf)
            #pragma unroll
            for (int r = 0; r < 4; ++r)
                red[w][16 * mf + 4 * g + r] = lsum[mf][r];
    }
    __syncthreads();
    if (tid < 64) {
        float s = red[0][tid] + red[1][tid] + red[2][tid] + red[3][tid];
        cvals[(size_t)bh * SEQ + i0 + tid] = 0.5f * log2f(s);
    }
}

// ---------------------------------------------------------------------------
// prescale_v: vT[bh][i][d] f16 -> vf16[bh][d][i] f16, scaled by 2^(-c_i/2).
// (cvals holds c/2 already.)
// ---------------------------------------------------------------------------
__global__ __launch_bounds__(256)
void prescale_v(const _Float16* __restrict__ vT, const float* __restrict__ cvals,
                _Float16* __restrict__ vf16)
{
    __shared__ float T[64][65];
    const int i0 = blockIdx.x * 64, bh = blockIdx.y;
    const int t = threadIdx.x, r = t >> 2, q = t & 3;
    const float cf = exp2f(-cvals[(size_t)bh * SEQ + i0 + r]);
    const _Float16* src = vT + ((size_t)bh * SEQ + i0 + r) * HD + q * 16;
    f16x8 a = *(const f16x8*)src, b = *(const f16x8*)(src + 8);
    #pragma unroll
    for (int k = 0; k < 8; ++k) {
        T[r][q * 16 + k]     = (float)a[k] * cf;
        T[r][q * 16 + 8 + k] = (float)b[k] * cf;
    }
    __syncthreads();
    f16x8 o0, o1;
    #pragma unroll
    for (int k = 0; k < 8; ++k) {
        o0[k] = (_Float16)T[q * 16 + k][r];
        o1[k] = (_Float16)T[q * 16 + 8 + k][r];
    }
    _Float16* dst = vf16 + ((size_t)bh * HD + r) * SEQ + i0 + q * 16;
    *(f16x8*)dst = o0; *(f16x8*)(dst + 8) = o1;
}

// ---------------------------------------------------------------------------
// Pass 2 v4: outT[j][d] = sum_i P^T[j][i] * V''^T[i][d], P = 2^(S - c/2).
// Direct-global K/V/c with ONE-CHUNK SOFTWARE PREFETCH (2x-unrolled ping/pong
// register sets); LDS only for double-buffered P; one barrier per chunk.
// ---------------------------------------------------------------------------
struct KVC { f16x8 k0, k1, v0, v1; float4 c; };

__device__ inline KVC loadKVC(const _Float16* tb, const _Float16* vb,
                              const float* cp, int i0, int w, int l15, int g)
{
    KVC r;
    const _Float16* kb = tb + (size_t)(i0 + 16 * w + l15) * 128 + 64 + g * 8;
    r.k0 = *(const f16x8*)(kb);
    r.k1 = *(const f16x8*)(kb + 32);
    const _Float16* vp = vb + (size_t)(16 * w + l15) * SEQ + i0 + g * 8;
    r.v0 = *(const f16x8*)(vp);
    r.v1 = *(const f16x8*)(vp + 32);
    r.c  = *(const float4*)(cp + i0 + 16 * w + 4 * g);
    return r;
}

__global__ __launch_bounds__(256, 4)
void attn_pass2(const _Float16* __restrict__ qkT, const _Float16* __restrict__ vf16,
                const float* __restrict__ cvals,
                ushort* __restrict__ aoth, ushort* __restrict__ aotl)
{
    const int jt = blockIdx.x, bh = blockIdx.y;
    const int b = bh >> 3, h = bh & 7;
    const _Float16* tb = qkT + ((size_t)bh * SEQ) * 128;
    const _Float16* vb = vf16 + ((size_t)bh * HD) * SEQ;
    const float* cp = cvals + (size_t)bh * SEQ;
    const int j0 = jt * 64;

    __shared__ __align__(16) _Float16 Pt[2][4096];   // [buf][64 j][64 i] swizzled

    const int tid = threadIdx.x;
    const int w = tid >> 6, lane = tid & 63, l15 = lane & 15, g = lane >> 4;

    // hoist Q B-frags: rows j = j0+16jf+l15, d = kh*32 + g*8
    f16x8 qf[4][2];
    #pragma unroll
    for (int jf = 0; jf < 4; ++jf) {
        const _Float16* qb = tb + (size_t)(j0 + 16 * jf + l15) * 128 + g * 8;
        qf[jf][0] = *(const f16x8*)(qb);
        qf[jf][1] = *(const f16x8*)(qb + 32);
    }

    f32x4 oacc[4] = {};

    auto body = [&](const KVC& cur, int buf) {
        _Float16* Pw = &Pt[buf][0];
        const f32x4 cinit = {-cur.c.x, -cur.c.y, -cur.c.z, -cur.c.w};
        #pragma unroll
        for (int jf = 0; jf < 4; ++jf) {
            f32x4 s = cinit;
            s = mfmaH(cur.k0, qf[jf][0], s);
            s = mfmaH(cur.k1, qf[jf][1], s);
            auto lo = __builtin_amdgcn_cvt_pkrtz(exp2f(s[0]), exp2f(s[1]));
            auto hi = __builtin_amdgcn_cvt_pkrtz(exp2f(s[2]), exp2f(s[3]));
            f16x4 pv;
            pv[0] = (_Float16)lo[0]; pv[1] = (_Float16)lo[1];
            pv[2] = (_Float16)hi[0]; pv[3] = (_Float16)hi[1];
            *(f16x4*)(Pw + (swz_off(16 * jf + l15, 32 * w + 8 * g) >> 1)) = pv;
        }
        __syncthreads();
        #pragma unroll
        for (int jf = 0; jf < 4; ++jf) {
            f16x8 p0 = fragH(Pw, 16 * jf + l15, g * 16);
            f16x8 p1 = fragH(Pw, 16 * jf + l15, 64 + g * 16);
            oacc[jf] = mfmaH(p0, cur.v0, oacc[jf]);
            oacc[jf] = mfmaH(p1, cur.v1, oacc[jf]);
        }
    };

    KVC cur = loadKVC(tb, vb, cp, 0, w, l15, g);
    for (int ic = 0; ic < 32; ic += 2) {
        // prefetch ic+1 while computing ic
        KVC nx1 = loadKVC(tb, vb, cp, (ic + 1) * 64, w, l15, g);
        body(cur, 0);
        // prefetch ic+2 (over-read at ic=30 stays in ws, never consumed)
        KVC nx2 = loadKVC(tb, vb, cp, (ic + 2) * 64, w, l15, g);
        body(nx1, 1);
        cur = nx2;
    }

    // write aoutT[j][h*64 + d] split bf16; d = 16w + l15 (32B coalesced segs)
    #pragma unroll
    for (int jf = 0; jf < 4; ++jf)
        #pragma unroll
        for (int r = 0; r < 4; ++r) {
            const int j = j0 + 16 * jf + 4 * g + r;
            const int ch = h * HD + 16 * w + l15;
            const size_t idx = ((size_t)b * SEQ + j) * CDIM + ch;
            float v = oacc[jf][r];
            ushort hi = bf16_rne(v);
            aoth[idx] = hi;
            aotl[idx] = bf16_rne(v - bf16_to_f(hi));
        }
}

// ---------------------------------------------------------------------------
extern "C" void kernel_launch(void* const* d_in, const int* in_sizes, int n_in,
                              void* d_out, int out_size, void* d_ws, size_t ws_size,
                              hipStream_t stream)
{
    const float* x      = (const float*)d_in[0];   // [4][512][2048]
    const float* w_qkv  = (const float*)d_in[1];   // [1536][512]
    const float* w_proj = (const float*)d_in[2];   // [512][512]
    const float* b_proj = (const float*)d_in[3];   // [512]
    float* out = (float*)d_out;                    // [4][512][2048]

    char* p = (char*)d_ws;
    auto alloc = [&](size_t bytes) { char* q = p; p += (bytes + 255) & ~(size_t)255; return q; };
    _Float16* qkT  = (_Float16*)alloc((size_t)NB * NHEAD * SEQ * 128 * 2); // 16 MB
    _Float16* vT   = (_Float16*)alloc((size_t)NB * NHEAD * SEQ * HD * 2);  // 8 MB
    float*    cvals = (float*)alloc((size_t)NB * NHEAD * SEQ * 4);         // 256 KB
    ushort*   xTh  = (ushort*)alloc((size_t)NB * SEQ * CDIM * 2);          // 8 MB
    ushort*   xTl  = (ushort*)alloc((size_t)NB * SEQ * CDIM * 2);          // 8 MB (spare)
    ushort*   wqh  = (ushort*)alloc((size_t)3 * CDIM * CDIM * 2);
    ushort*   wql  = (ushort*)alloc((size_t)3 * CDIM * CDIM * 2);
    ushort*   wph  = (ushort*)alloc((size_t)CDIM * CDIM * 2);
    ushort*   wpl  = (ushort*)alloc((size_t)CDIM * CDIM * 2);
    ushort*   aoth = (ushort*)alloc((size_t)NB * SEQ * CDIM * 2);          // 8 MB
    ushort*   aotl = (ushort*)alloc((size_t)NB * SEQ * CDIM * 2);          // 8 MB
    // vf16 aliases xTl: xT spare slot is never written; prescale_v writes it
    // before attn_pass2 reads it (stream-ordered, deterministic each replay).
    _Float16* vf16 = (_Float16*)xTl;

    dim3 blk(256);
    // weight splits + input transpose (plain bf16)
    conv_w<<<dim3(512), blk, 0, stream>>>(w_qkv, w_proj, wqh, wql, wph, wpl);
    conv_x<<<dim3(SEQ / 64, CDIM / 64, NB), blk, 0, stream>>>(x, xTh);
    // qkv: D[seq][ch] -> qkT fp16 (K*SL) + vT fp16 (A plain, B split: 2 terms)
    gemm_sp<0><<<dim3(12, 16, NB), blk, 0, stream>>>(
        xTh, nullptr, (size_t)SEQ * CDIM, wqh, wql, 0,
        qkT, vT, nullptr, nullptr);
    // softmax row constants (c/2, log2 domain)
    attn_pass1<<<dim3(SEQ / 64, NB * NHEAD), blk, 0, stream>>>(qkT, cvals);
    // V'' = v * 2^(-c/2), transposed to [d][i] fp16
    prescale_v<<<dim3(SEQ / 64, NB * NHEAD), blk, 0, stream>>>(vT, cvals, vf16);
    // attention -> aoutT split bf16
    attn_pass2<<<dim3(SEQ / 64, NB * NHEAD), blk, 0, stream>>>(
        qkT, vf16, cvals, aoth, aotl);
    // proj: D[co][seq] = w_proj @ aout + bias (3-term split)
    gemm_sp<1><<<dim3(16, 4, NB), blk, 0, stream>>>(
        wph, wpl, 0, aoth, aotl, (size_t)SEQ * CDIM,
        nullptr, nullptr, out, b_proj);
}